// Round 10
// baseline (98.772 us; speedup 1.0000x reference)
//
#include <hip/hip_runtime.h>

// SpatialCrossAttention (BEVFormer) — 2 kernels:
//  A) vproj : value @ Wv + bv -> vhw bf16 (register-tiled 32-row GEMM)
//  B) attn  : 128-thread blocks, wave = 2 queries.
//             fused qproj (float4 weight loads) + packed precompute +
//             dwordx2 bf16 gather (8 lanes/head, 4 acc) + float4 Wp outproj.

#define S_DIM 6
#define N_DIM 10000
#define C_DIM 128
#define M_DIM 3680
#define H_DIM 4
#define P_DIM 8
#define DH    32
#define HF    46
#define WF    80

#define G_Q   4
#define NENT  (S_DIM * P_DIM * H_DIM)             // 192
#define VHW_SHORTS (S_DIM * H_DIM * M_DIM * DH)   // 2,826,240

__device__ __forceinline__ float bfl(unsigned u) { return __uint_as_float(u << 16); }
__device__ __forceinline__ float bfh(unsigned u) { return __uint_as_float(u & 0xffff0000u); }
__device__ __forceinline__ unsigned short f2bf(float f) {
    unsigned b = __float_as_uint(f);
    b += 0x7FFFu + ((b >> 16) & 1u);   // RNE
    return (unsigned short)(b >> 16);
}

// ---------------------------------------------------------------- kernel A
// 32 rows/block, 256 threads: thread tile = 4 rows x 4 cols.
__global__ __launch_bounds__(256) void vproj_kernel(
    const float* __restrict__ value,   // (S*M, C)
    const float* __restrict__ Wv,      // (C, C)
    const float* __restrict__ bv,      // (C)
    unsigned short* __restrict__ vhw)  // (S, H, M, DH) bf16
{
    const int row0 = blockIdx.x * 32;
    const int t = threadIdx.x;
    const int tc = t & 31, tr = t >> 5;   // tr in [0,8)
    const int c0 = tc * 4, r0 = tr * 4;
    __shared__ float vs[32][C_DIM];       // 16 KB

    for (int i = t; i < 32 * 32; i += 256) {
        const int row = i >> 5, c4 = (i & 31) * 4;
        *(float4*)&vs[row][c4] =
            *(const float4*)&value[(size_t)(row0 + row) * C_DIM + c4];
    }
    __syncthreads();

    float acc[4][4];
#pragma unroll
    for (int r = 0; r < 4; ++r)
#pragma unroll
        for (int c = 0; c < 4; ++c) acc[r][c] = 0.f;

    for (int k = 0; k < C_DIM; k += 4) {
        const float4 w0 = *(const float4*)&Wv[(k + 0) * C_DIM + c0];
        const float4 w1 = *(const float4*)&Wv[(k + 1) * C_DIM + c0];
        const float4 w2 = *(const float4*)&Wv[(k + 2) * C_DIM + c0];
        const float4 w3 = *(const float4*)&Wv[(k + 3) * C_DIM + c0];
#pragma unroll
        for (int r = 0; r < 4; ++r) {
            const float4 v = *(const float4*)&vs[r0 + r][k];
            acc[r][0] = fmaf(v.x, w0.x, acc[r][0]);
            acc[r][0] = fmaf(v.y, w1.x, acc[r][0]);
            acc[r][0] = fmaf(v.z, w2.x, acc[r][0]);
            acc[r][0] = fmaf(v.w, w3.x, acc[r][0]);
            acc[r][1] = fmaf(v.x, w0.y, acc[r][1]);
            acc[r][1] = fmaf(v.y, w1.y, acc[r][1]);
            acc[r][1] = fmaf(v.z, w2.y, acc[r][1]);
            acc[r][1] = fmaf(v.w, w3.y, acc[r][1]);
            acc[r][2] = fmaf(v.x, w0.z, acc[r][2]);
            acc[r][2] = fmaf(v.y, w1.z, acc[r][2]);
            acc[r][2] = fmaf(v.z, w2.z, acc[r][2]);
            acc[r][2] = fmaf(v.w, w3.z, acc[r][2]);
            acc[r][3] = fmaf(v.x, w0.w, acc[r][3]);
            acc[r][3] = fmaf(v.y, w1.w, acc[r][3]);
            acc[r][3] = fmaf(v.z, w2.w, acc[r][3]);
            acc[r][3] = fmaf(v.w, w3.w, acc[r][3]);
        }
    }

    const float4 bb = *(const float4*)&bv[c0];
    const int h = c0 >> 5, dh0 = c0 & 31;
#pragma unroll
    for (int r = 0; r < 4; ++r) {
        const int row = row0 + r0 + r;
        const int s = row / M_DIM, m = row - s * M_DIM;
        ushort4 o;
        o.x = f2bf(acc[r][0] + bb.x);
        o.y = f2bf(acc[r][1] + bb.y);
        o.z = f2bf(acc[r][2] + bb.z);
        o.w = f2bf(acc[r][3] + bb.w);
        *(ushort4*)&vhw[(((size_t)s * H_DIM + h) * M_DIM + m) * DH + dh0] = o;
    }
}

// ---------------------------------------------------------------- kernel B
__global__ __launch_bounds__(128, 4) void attn_kernel(
    const unsigned short* __restrict__ vhw,   // (S,H,M,DH) bf16
    const float* __restrict__ query,
    const float* __restrict__ query_pos,
    const float* __restrict__ Wo, const float* __restrict__ bo,   // (C,64),(64)
    const float* __restrict__ Wa, const float* __restrict__ ba,   // (C,32),(32)
    const float* __restrict__ refpts,   // (S,1,N,4,2)
    const void* __restrict__ bev_mask,  // (S,1,N,4) bool/int32
    const void* __restrict__ sshapes,   // int probe
    const float* __restrict__ Wp, const float* __restrict__ bp,
    float* __restrict__ out)            // (1,N,C)
{
    const int n0 = blockIdx.x * G_Q;
    const int t = threadIdx.x;          // 128

    __shared__ float  qs[G_Q][C_DIM];                     // 2 KB
    __shared__ float  s_offr[G_Q][64];                    // 1 KB
    __shared__ float  s_attw[G_Q][32];                    // 0.5 KB
    __shared__ uint2  s_pixd[G_Q][S_DIM][P_DIM][H_DIM];   // 6 KB (c00|c10, c01|c11)
    __shared__ uint2  s_wbd[G_Q][S_DIM][P_DIM][H_DIM];    // 6 KB (bf16 w00|w10, w01|w11)
    __shared__ float  s_slots[G_Q][C_DIM];                // 2 KB
    __shared__ int    s_mask[G_Q][S_DIM];
    __shared__ float  s_inv[G_Q];

    // ---- phase 0: queries + masks
    for (int i = t; i < G_Q * C_DIM; i += 128) {
        const int g = i >> 7, c = i & 127;
        const size_t a = (size_t)(n0 + g) * C_DIM + c;
        qs[g][c] = query[a] + query_pos[a];
    }
    if (t < G_Q * S_DIM) {   // 24
        const int g = t / S_DIM, s = t - g * S_DIM;
        const int n = n0 + g;
        const int* ss32 = (const int*)sshapes;
        const bool i32mode = (ss32[1] == WF);
        int mk;
        if (i32mode) {
            const int* bm = (const int*)bev_mask + ((size_t)s * N_DIM + n) * 4;
            mk = (bm[0] | bm[1] | bm[2] | bm[3]) ? 1 : 0;
        } else {
            const unsigned char* bm =
                (const unsigned char*)bev_mask + ((size_t)s * N_DIM + n) * 4;
            mk = (bm[0] | bm[1] | bm[2] | bm[3]) ? 1 : 0;
        }
        s_mask[g][s] = mk;
    }
    __syncthreads();
    if (t < G_Q) {
        int c = 0;
#pragma unroll
        for (int s = 0; s < S_DIM; ++s) c += s_mask[t][s];
        s_inv[t] = 1.f / fmaxf((float)c, 1.f);
    }

    // ---- phase 1: fused qproj, float4 weight loads.
    //      wave0: offsets (thread = (g, j-quad)); wave1: logits + softmax.
    if (t < 64) {
        const int g = t >> 4, j0 = (t & 15) * 4;
        float a0 = 0.f, a1 = 0.f, a2 = 0.f, a3 = 0.f;
        for (int k = 0; k < C_DIM; k += 4) {
            const float4 q4 = *(const float4*)&qs[g][k];
            float4 w;
            w = *(const float4*)&Wo[(k + 0) * 64 + j0];
            a0 = fmaf(q4.x, w.x, a0); a1 = fmaf(q4.x, w.y, a1);
            a2 = fmaf(q4.x, w.z, a2); a3 = fmaf(q4.x, w.w, a3);
            w = *(const float4*)&Wo[(k + 1) * 64 + j0];
            a0 = fmaf(q4.y, w.x, a0); a1 = fmaf(q4.y, w.y, a1);
            a2 = fmaf(q4.y, w.z, a2); a3 = fmaf(q4.y, w.w, a3);
            w = *(const float4*)&Wo[(k + 2) * 64 + j0];
            a0 = fmaf(q4.z, w.x, a0); a1 = fmaf(q4.z, w.y, a1);
            a2 = fmaf(q4.z, w.z, a2); a3 = fmaf(q4.z, w.w, a3);
            w = *(const float4*)&Wo[(k + 3) * 64 + j0];
            a0 = fmaf(q4.w, w.x, a0); a1 = fmaf(q4.w, w.y, a1);
            a2 = fmaf(q4.w, w.z, a2); a3 = fmaf(q4.w, w.w, a3);
        }
        const float4 b4 = *(const float4*)&bo[j0];
        float4 r; r.x = a0 + b4.x; r.y = a1 + b4.y; r.z = a2 + b4.z; r.w = a3 + b4.w;
        *(float4*)&s_offr[g][j0] = r;
    } else {
        const int i = t - 64;           // lane in wave 1
        const int g = i >> 3, j0 = (i & 7) * 4;
        float a0 = 0.f, a1 = 0.f, a2 = 0.f, a3 = 0.f;
        for (int k = 0; k < C_DIM; k += 4) {
            const float4 q4 = *(const float4*)&qs[g][k];
            float4 w;
            w = *(const float4*)&Wa[(k + 0) * 32 + j0];
            a0 = fmaf(q4.x, w.x, a0); a1 = fmaf(q4.x, w.y, a1);
            a2 = fmaf(q4.x, w.z, a2); a3 = fmaf(q4.x, w.w, a3);
            w = *(const float4*)&Wa[(k + 1) * 32 + j0];
            a0 = fmaf(q4.y, w.x, a0); a1 = fmaf(q4.y, w.y, a1);
            a2 = fmaf(q4.y, w.z, a2); a3 = fmaf(q4.y, w.w, a3);
            w = *(const float4*)&Wa[(k + 2) * 32 + j0];
            a0 = fmaf(q4.z, w.x, a0); a1 = fmaf(q4.z, w.y, a1);
            a2 = fmaf(q4.z, w.z, a2); a3 = fmaf(q4.z, w.w, a3);
            w = *(const float4*)&Wa[(k + 3) * 32 + j0];
            a0 = fmaf(q4.w, w.x, a0); a1 = fmaf(q4.w, w.y, a1);
            a2 = fmaf(q4.w, w.z, a2); a3 = fmaf(q4.w, w.w, a3);
        }
        const float4 b4 = *(const float4*)&ba[j0];
        a0 += b4.x; a1 += b4.y; a2 += b4.z; a3 += b4.w;
        // softmax over 8 (this thread's 4 + partner lane's 4, same head)
        float m4 = fmaxf(fmaxf(a0, a1), fmaxf(a2, a3));
        const float m8 = fmaxf(m4, __shfl_xor(m4, 1));
        const float e0 = expf(a0 - m8), e1 = expf(a1 - m8);
        const float e2 = expf(a2 - m8), e3 = expf(a3 - m8);
        float s4 = e0 + e1 + e2 + e3;
        const float s8 = s4 + __shfl_xor(s4, 1);
        const float rs = 1.f / s8;
        float4 r; r.x = e0 * rs; r.y = e1 * rs; r.z = e2 * rs; r.w = e3 * rs;
        *(float4*)&s_attw[g][j0] = r;
    }
    __syncthreads();

    // ---- phase 1b: per-(g,s,p,h) packed pixel pairs + bf16 weights
    for (int i = t; i < G_Q * NENT; i += 128) {
        const int g = i / NENT;
        const int e = i - g * NENT;      // e in [0,192)
        const int s = e >> 5;
        const int rem = e & 31;          // p*4 + h
        const int p = rem >> 2, h = rem & 3;
        const int hp = h * P_DIM + p;
        const int d = p & 3;
        const int n = n0 + g;

        const float aw = s_attw[g][hp];
        const float offx = s_offr[g][hp * 2 + 0] / (float)WF;
        const float offy = s_offr[g][hp * 2 + 1] / (float)HF;
        const float refx = refpts[(((size_t)s * N_DIM + n) * 4 + d) * 2 + 0];
        const float refy = refpts[(((size_t)s * N_DIM + n) * 4 + d) * 2 + 1];

        const float x = (refx + offx) * (float)WF - 0.5f;
        const float y = (refy + offy) * (float)HF - 0.5f;
        const float x0f = floorf(x), y0f = floorf(y);
        const float lx = x - x0f, ly = y - y0f;
        const int x0 = (int)x0f, y0 = (int)y0f;
        const int x1 = x0 + 1, y1 = y0 + 1;

        const bool vx0 = (x0 >= 0) & (x0 < WF);
        const bool vx1 = (x1 >= 0) & (x1 < WF);
        const bool vy0 = (y0 >= 0) & (y0 < HF);
        const bool vy1 = (y1 >= 0) & (y1 < HF);

        const unsigned cx0 = (unsigned)min(max(x0, 0), WF - 1);
        const unsigned cx1 = (unsigned)min(max(x1, 0), WF - 1);
        const unsigned cy0 = (unsigned)min(max(y0, 0), HF - 1);
        const unsigned cy1 = (unsigned)min(max(y1, 0), HF - 1);

        const unsigned p00 = cy0 * WF + cx0;
        const unsigned p10 = cy0 * WF + cx1;
        const unsigned p01 = cy1 * WF + cx0;
        const unsigned p11 = cy1 * WF + cx1;
        s_pixd[g][s][p][h] = make_uint2(p00 | (p10 << 16), p01 | (p11 << 16));

        const float wx0 = 1.f - lx, wy0 = 1.f - ly;
        const float w00 = (vx0 & vy0) ? wx0 * wy0 * aw : 0.f;
        const float w10 = (vx1 & vy0) ? lx  * wy0 * aw : 0.f;
        const float w01 = (vx0 & vy1) ? wx0 * ly  * aw : 0.f;
        const float w11 = (vx1 & vy1) ? lx  * ly  * aw : 0.f;
        s_wbd[g][s][p][h] = make_uint2(
            (unsigned)f2bf(w00) | ((unsigned)f2bf(w10) << 16),
            (unsigned)f2bf(w01) | ((unsigned)f2bf(w11) << 16));
    }
    __syncthreads();

    // ---- phase 2: gather — wave = 2 queries, 8 lanes/head, dwordx2 loads
    {
        const char* vb = (const char*)vhw;
        const int w = t >> 6;               // wave 0/1
        const int lane = t & 63;
        const int q = (w << 1) | (lane >> 5);
        const int l32 = lane & 31;
        const int h = l32 >> 3;
        const int dq8 = (l32 & 7) * 8;      // byte offset of dh quad
        float a0 = 0.f, a1 = 0.f, a2 = 0.f, a3 = 0.f;

        for (int s = 0; s < S_DIM; ++s) {
            if (!s_mask[q][s]) continue;
            const char* vbs = vb + (((s * H_DIM + h) * M_DIM) * (DH * 2) + dq8);
#pragma unroll
            for (int pg = 0; pg < 4; ++pg) {   // 2 points per iter
                const uint2 pa = s_pixd[q][s][pg * 2 + 0][h];
                const uint2 pb = s_pixd[q][s][pg * 2 + 1][h];
                const uint2 u0 = *(const uint2*)(vbs + ((pa.x <<  6) & 0x3fffc0u));
                const uint2 u1 = *(const uint2*)(vbs + ((pa.x >> 10) & 0x3fffc0u));
                const uint2 u2 = *(const uint2*)(vbs + ((pa.y <<  6) & 0x3fffc0u));
                const uint2 u3 = *(const uint2*)(vbs + ((pa.y >> 10) & 0x3fffc0u));
                const uint2 u4 = *(const uint2*)(vbs + ((pb.x <<  6) & 0x3fffc0u));
                const uint2 u5 = *(const uint2*)(vbs + ((pb.x >> 10) & 0x3fffc0u));
                const uint2 u6 = *(const uint2*)(vbs + ((pb.y <<  6) & 0x3fffc0u));
                const uint2 u7 = *(const uint2*)(vbs + ((pb.y >> 10) & 0x3fffc0u));
                const uint2 wa = s_wbd[q][s][pg * 2 + 0][h];
                const uint2 wb = s_wbd[q][s][pg * 2 + 1][h];
                const float w00 = bfl(wa.x), w10 = bfh(wa.x);
                const float w01 = bfl(wa.y), w11 = bfh(wa.y);
                const float x00 = bfl(wb.x), x10 = bfh(wb.x);
                const float x01 = bfl(wb.y), x11 = bfh(wb.y);
                a0 = fmaf(w00, bfl(u0.x), a0); a1 = fmaf(w00, bfh(u0.x), a1);
                a2 = fmaf(w00, bfl(u0.y), a2); a3 = fmaf(w00, bfh(u0.y), a3);
                a0 = fmaf(w10, bfl(u1.x), a0); a1 = fmaf(w10, bfh(u1.x), a1);
                a2 = fmaf(w10, bfl(u1.y), a2); a3 = fmaf(w10, bfh(u1.y), a3);
                a0 = fmaf(w01, bfl(u2.x), a0); a1 = fmaf(w01, bfh(u2.x), a1);
                a2 = fmaf(w01, bfl(u2.y), a2); a3 = fmaf(w01, bfh(u2.y), a3);
                a0 = fmaf(w11, bfl(u3.x), a0); a1 = fmaf(w11, bfh(u3.x), a1);
                a2 = fmaf(w11, bfl(u3.y), a2); a3 = fmaf(w11, bfh(u3.y), a3);
                a0 = fmaf(x00, bfl(u4.x), a0); a1 = fmaf(x00, bfh(u4.x), a1);
                a2 = fmaf(x00, bfl(u4.y), a2); a3 = fmaf(x00, bfh(u4.y), a3);
                a0 = fmaf(x10, bfl(u5.x), a0); a1 = fmaf(x10, bfh(u5.x), a1);
                a2 = fmaf(x10, bfl(u5.y), a2); a3 = fmaf(x10, bfh(u5.y), a3);
                a0 = fmaf(x01, bfl(u6.x), a0); a1 = fmaf(x01, bfh(u6.x), a1);
                a2 = fmaf(x01, bfl(u6.y), a2); a3 = fmaf(x01, bfh(u6.y), a3);
                a0 = fmaf(x11, bfl(u7.x), a0); a1 = fmaf(x11, bfh(u7.x), a1);
                a2 = fmaf(x11, bfl(u7.y), a2); a3 = fmaf(x11, bfh(u7.y), a3);
            }
        }
        const float inv = s_inv[q];
        float4 r; r.x = a0 * inv; r.y = a1 * inv; r.z = a2 * inv; r.w = a3 * inv;
        *(float4*)&s_slots[q][h * 32 + (l32 & 7) * 4] = r;
    }
    __syncthreads();

    // ---- phase 3: out projection, thread = (c-quad, query-pair); wave0 only
    if (t < 64) {
        const int cq = (t & 31) * 4, qp = t >> 5;
        const int g0 = qp * 2;
        float a0[4] = {0.f, 0.f, 0.f, 0.f};
        float a1[4] = {0.f, 0.f, 0.f, 0.f};
        for (int k = 0; k < C_DIM; k += 4) {
            const float4 s0 = *(const float4*)&s_slots[g0][k];
            const float4 s1 = *(const float4*)&s_slots[g0 + 1][k];
            float4 w;
            w = *(const float4*)&Wp[(k + 0) * C_DIM + cq];
            a0[0] = fmaf(s0.x, w.x, a0[0]); a0[1] = fmaf(s0.x, w.y, a0[1]);
            a0[2] = fmaf(s0.x, w.z, a0[2]); a0[3] = fmaf(s0.x, w.w, a0[3]);
            a1[0] = fmaf(s1.x, w.x, a1[0]); a1[1] = fmaf(s1.x, w.y, a1[1]);
            a1[2] = fmaf(s1.x, w.z, a1[2]); a1[3] = fmaf(s1.x, w.w, a1[3]);
            w = *(const float4*)&Wp[(k + 1) * C_DIM + cq];
            a0[0] = fmaf(s0.y, w.x, a0[0]); a0[1] = fmaf(s0.y, w.y, a0[1]);
            a0[2] = fmaf(s0.y, w.z, a0[2]); a0[3] = fmaf(s0.y, w.w, a0[3]);
            a1[0] = fmaf(s1.y, w.x, a1[0]); a1[1] = fmaf(s1.y, w.y, a1[1]);
            a1[2] = fmaf(s1.y, w.z, a1[2]); a1[3] = fmaf(s1.y, w.w, a1[3]);
            w = *(const float4*)&Wp[(k + 2) * C_DIM + cq];
            a0[0] = fmaf(s0.z, w.x, a0[0]); a0[1] = fmaf(s0.z, w.y, a0[1]);
            a0[2] = fmaf(s0.z, w.z, a0[2]); a0[3] = fmaf(s0.z, w.w, a0[3]);
            a1[0] = fmaf(s1.z, w.x, a1[0]); a1[1] = fmaf(s1.z, w.y, a1[1]);
            a1[2] = fmaf(s1.z, w.z, a1[2]); a1[3] = fmaf(s1.z, w.w, a1[3]);
            w = *(const float4*)&Wp[(k + 3) * C_DIM + cq];
            a0[0] = fmaf(s0.w, w.x, a0[0]); a0[1] = fmaf(s0.w, w.y, a0[1]);
            a0[2] = fmaf(s0.w, w.z, a0[2]); a0[3] = fmaf(s0.w, w.w, a0[3]);
            a1[0] = fmaf(s1.w, w.x, a1[0]); a1[1] = fmaf(s1.w, w.y, a1[1]);
            a1[2] = fmaf(s1.w, w.z, a1[2]); a1[3] = fmaf(s1.w, w.w, a1[3]);
        }
        const float4 bb = *(const float4*)&bp[cq];
        const int na = n0 + g0;
        const float4 q0 = *(const float4*)&query[(size_t)na * C_DIM + cq];
        const float4 q1 = *(const float4*)&query[(size_t)(na + 1) * C_DIM + cq];
        float4 o0, o1;
        o0.x = a0[0] + bb.x + q0.x; o0.y = a0[1] + bb.y + q0.y;
        o0.z = a0[2] + bb.z + q0.z; o0.w = a0[3] + bb.w + q0.w;
        o1.x = a1[0] + bb.x + q1.x; o1.y = a1[1] + bb.y + q1.y;
        o1.z = a1[2] + bb.z + q1.z; o1.w = a1[3] + bb.w + q1.w;
        *(float4*)&out[(size_t)na * C_DIM + cq]       = o0;
        *(float4*)&out[(size_t)(na + 1) * C_DIM + cq] = o1;
    }
}

// ---------------------------------------------------------------- launch
extern "C" void kernel_launch(void* const* d_in, const int* in_sizes, int n_in,
                              void* d_out, int out_size, void* d_ws, size_t ws_size,
                              hipStream_t stream) {
    const float* query     = (const float*)d_in[0];
    // d_in[1] = key (unused by reference)
    const float* value     = (const float*)d_in[2];
    const float* query_pos = (const float*)d_in[3];
    const float* refpts    = (const float*)d_in[4];
    const float* Wv        = (const float*)d_in[5];
    const float* bv        = (const float*)d_in[6];
    const float* Wo        = (const float*)d_in[7];
    const float* bo        = (const float*)d_in[8];
    const float* Wa        = (const float*)d_in[9];
    const float* ba        = (const float*)d_in[10];
    const float* Wp        = (const float*)d_in[11];
    const float* bp        = (const float*)d_in[12];
    const void*  sshapes   = d_in[13];
    const void*  bev_mask  = d_in[14];

    unsigned short* vhw = (unsigned short*)d_ws;
    float* outp = (float*)d_out;

    hipLaunchKernelGGL(vproj_kernel, dim3((S_DIM * M_DIM) / 32), dim3(256), 0, stream,
                       value, Wv, bv, vhw);
    hipLaunchKernelGGL(attn_kernel, dim3(N_DIM / G_Q), dim3(128), 0, stream,
                       vhw, query, query_pos, Wo, bo, Wa, ba,
                       refpts, bev_mask, sshapes, Wp, bp, outp);
}

// Round 11
// 88.477 us; speedup vs baseline: 1.1163x; 1.1163x over previous
//
#include <hip/hip_runtime.h>

// SpatialCrossAttention (BEVFormer) — 2 kernels:
//  A) vproj : value @ Wv + bv -> vhw bf16 (register-tiled 32-row GEMM)
//  B) attn  : R8 structure (256 thr, G_Q=4, 18.4KB LDS) with phase-1 reworked:
//             float4 weight loads + in-wave k-split (shfl combine). Phases 0/1b/2/3
//             identical to the measured-61us R8 kernel.

#define S_DIM 6
#define N_DIM 10000
#define C_DIM 128
#define M_DIM 3680
#define H_DIM 4
#define P_DIM 8
#define DH    32
#define HF    46
#define WF    80

#define G_Q   4
#define NENT  (S_DIM * P_DIM * H_DIM)             // 192
#define VHW_SHORTS (S_DIM * H_DIM * M_DIM * DH)   // 2,826,240

__device__ __forceinline__ float bfl(unsigned u) { return __uint_as_float(u << 16); }
__device__ __forceinline__ float bfh(unsigned u) { return __uint_as_float(u & 0xffff0000u); }
__device__ __forceinline__ unsigned short f2bf(float f) {
    unsigned b = __float_as_uint(f);
    b += 0x7FFFu + ((b >> 16) & 1u);   // RNE
    return (unsigned short)(b >> 16);
}

// ---------------------------------------------------------------- kernel A
// 32 rows/block, 256 threads: thread tile = 4 rows x 4 cols.
__global__ __launch_bounds__(256) void vproj_kernel(
    const float* __restrict__ value,   // (S*M, C)
    const float* __restrict__ Wv,      // (C, C)
    const float* __restrict__ bv,      // (C)
    unsigned short* __restrict__ vhw)  // (S, H, M, DH) bf16
{
    const int row0 = blockIdx.x * 32;
    const int t = threadIdx.x;
    const int tc = t & 31, tr = t >> 5;   // tr in [0,8)
    const int c0 = tc * 4, r0 = tr * 4;
    __shared__ float vs[32][C_DIM];       // 16 KB

    for (int i = t; i < 32 * 32; i += 256) {
        const int row = i >> 5, c4 = (i & 31) * 4;
        *(float4*)&vs[row][c4] =
            *(const float4*)&value[(size_t)(row0 + row) * C_DIM + c4];
    }
    __syncthreads();

    float acc[4][4];
#pragma unroll
    for (int r = 0; r < 4; ++r)
#pragma unroll
        for (int c = 0; c < 4; ++c) acc[r][c] = 0.f;

    for (int k = 0; k < C_DIM; k += 4) {
        const float4 w0 = *(const float4*)&Wv[(k + 0) * C_DIM + c0];
        const float4 w1 = *(const float4*)&Wv[(k + 1) * C_DIM + c0];
        const float4 w2 = *(const float4*)&Wv[(k + 2) * C_DIM + c0];
        const float4 w3 = *(const float4*)&Wv[(k + 3) * C_DIM + c0];
#pragma unroll
        for (int r = 0; r < 4; ++r) {
            const float4 v = *(const float4*)&vs[r0 + r][k];
            acc[r][0] = fmaf(v.x, w0.x, acc[r][0]);
            acc[r][0] = fmaf(v.y, w1.x, acc[r][0]);
            acc[r][0] = fmaf(v.z, w2.x, acc[r][0]);
            acc[r][0] = fmaf(v.w, w3.x, acc[r][0]);
            acc[r][1] = fmaf(v.x, w0.y, acc[r][1]);
            acc[r][1] = fmaf(v.y, w1.y, acc[r][1]);
            acc[r][1] = fmaf(v.z, w2.y, acc[r][1]);
            acc[r][1] = fmaf(v.w, w3.y, acc[r][1]);
            acc[r][2] = fmaf(v.x, w0.z, acc[r][2]);
            acc[r][2] = fmaf(v.y, w1.z, acc[r][2]);
            acc[r][2] = fmaf(v.z, w2.z, acc[r][2]);
            acc[r][2] = fmaf(v.w, w3.z, acc[r][2]);
            acc[r][3] = fmaf(v.x, w0.w, acc[r][3]);
            acc[r][3] = fmaf(v.y, w1.w, acc[r][3]);
            acc[r][3] = fmaf(v.z, w2.w, acc[r][3]);
            acc[r][3] = fmaf(v.w, w3.w, acc[r][3]);
        }
    }

    const float4 bb = *(const float4*)&bv[c0];
    const int h = c0 >> 5, dh0 = c0 & 31;
#pragma unroll
    for (int r = 0; r < 4; ++r) {
        const int row = row0 + r0 + r;
        const int s = row / M_DIM, m = row - s * M_DIM;
        ushort4 o;
        o.x = f2bf(acc[r][0] + bb.x);
        o.y = f2bf(acc[r][1] + bb.y);
        o.z = f2bf(acc[r][2] + bb.z);
        o.w = f2bf(acc[r][3] + bb.w);
        *(ushort4*)&vhw[(((size_t)s * H_DIM + h) * M_DIM + m) * DH + dh0] = o;
    }
}

// ---------------------------------------------------------------- kernel B
__global__ __launch_bounds__(256, 4) void attn_kernel(
    const unsigned short* __restrict__ vhw,   // (S,H,M,DH) bf16
    const float* __restrict__ query,
    const float* __restrict__ query_pos,
    const float* __restrict__ Wo, const float* __restrict__ bo,   // (C,64),(64)
    const float* __restrict__ Wa, const float* __restrict__ ba,   // (C,32),(32)
    const float* __restrict__ refpts,   // (S,1,N,4,2)
    const void* __restrict__ bev_mask,  // (S,1,N,4) bool/int32
    const void* __restrict__ sshapes,   // int probe
    const float* __restrict__ Wp, const float* __restrict__ bp,
    float* __restrict__ out)            // (1,N,C)
{
    const int n0 = blockIdx.x * G_Q;
    const int t = threadIdx.x;          // 256

    __shared__ float  qs[G_Q][C_DIM];                     // 2 KB
    __shared__ float  s_offr[G_Q][64];                    // 1 KB
    __shared__ float  s_attw[G_Q][32];                    // 0.5 KB
    __shared__ uint2  s_pixd[G_Q][S_DIM][P_DIM][H_DIM];   // 6 KB (c00|c10, c01|c11)
    __shared__ uint2  s_wbd[G_Q][S_DIM][P_DIM][H_DIM];    // 6 KB (bf16 w00|w10, w01|w11)
    __shared__ float  s_slots[G_Q][C_DIM];                // 2 KB
    __shared__ int    s_mask[G_Q][S_DIM];
    __shared__ float  s_inv[G_Q];

    // ---- phase 0: queries + masks
    for (int i = t; i < G_Q * C_DIM; i += 256) {
        const int g = i >> 7, c = i & 127;
        const size_t a = (size_t)(n0 + g) * C_DIM + c;
        qs[g][c] = query[a] + query_pos[a];
    }
    if (t < G_Q * S_DIM) {   // 24
        const int g = t / S_DIM, s = t - g * S_DIM;
        const int n = n0 + g;
        const int* ss32 = (const int*)sshapes;
        const bool i32mode = (ss32[1] == WF);
        int mk;
        if (i32mode) {
            const int* bm = (const int*)bev_mask + ((size_t)s * N_DIM + n) * 4;
            mk = (bm[0] | bm[1] | bm[2] | bm[3]) ? 1 : 0;
        } else {
            const unsigned char* bm =
                (const unsigned char*)bev_mask + ((size_t)s * N_DIM + n) * 4;
            mk = (bm[0] | bm[1] | bm[2] | bm[3]) ? 1 : 0;
        }
        s_mask[g][s] = mk;
    }
    __syncthreads();
    if (t < G_Q) {
        int c = 0;
#pragma unroll
        for (int s = 0; s < S_DIM; ++s) c += s_mask[t][s];
        s_inv[t] = 1.f / fmaxf((float)c, 1.f);
    }

    // ---- phase 1: fused qproj — float4 weight loads, in-wave k-split.
    //      threads 0-127  : Wo, thread = (g, j-quad, k-half)
    //      threads 128-191: Wa + softmax, thread = (g, j-quad, k-half)
    if (t < 128) {
        const int task = t >> 1, kh = t & 1;
        const int g = task >> 4, j0 = (task & 15) * 4;
        const int kb = kh * 64;
        float a0 = 0.f, a1 = 0.f, a2 = 0.f, a3 = 0.f;
        for (int kk = 0; kk < 64; kk += 4) {
            const float4 q4 = *(const float4*)&qs[g][kb + kk];
            float4 w;
            w = *(const float4*)&Wo[(kb + kk + 0) * 64 + j0];
            a0 = fmaf(q4.x, w.x, a0); a1 = fmaf(q4.x, w.y, a1);
            a2 = fmaf(q4.x, w.z, a2); a3 = fmaf(q4.x, w.w, a3);
            w = *(const float4*)&Wo[(kb + kk + 1) * 64 + j0];
            a0 = fmaf(q4.y, w.x, a0); a1 = fmaf(q4.y, w.y, a1);
            a2 = fmaf(q4.y, w.z, a2); a3 = fmaf(q4.y, w.w, a3);
            w = *(const float4*)&Wo[(kb + kk + 2) * 64 + j0];
            a0 = fmaf(q4.z, w.x, a0); a1 = fmaf(q4.z, w.y, a1);
            a2 = fmaf(q4.z, w.z, a2); a3 = fmaf(q4.z, w.w, a3);
            w = *(const float4*)&Wo[(kb + kk + 3) * 64 + j0];
            a0 = fmaf(q4.w, w.x, a0); a1 = fmaf(q4.w, w.y, a1);
            a2 = fmaf(q4.w, w.z, a2); a3 = fmaf(q4.w, w.w, a3);
        }
        a0 += __shfl_xor(a0, 1); a1 += __shfl_xor(a1, 1);
        a2 += __shfl_xor(a2, 1); a3 += __shfl_xor(a3, 1);
        if (kh == 0) {
            const float4 b4 = *(const float4*)&bo[j0];
            float4 r; r.x = a0 + b4.x; r.y = a1 + b4.y;
            r.z = a2 + b4.z; r.w = a3 + b4.w;
            *(float4*)&s_offr[g][j0] = r;
        }
    } else if (t < 192) {
        const int i = t - 128;
        const int task = i >> 1, kh = i & 1;
        const int g = task >> 3, j0 = (task & 7) * 4;
        const int kb = kh * 64;
        float a0 = 0.f, a1 = 0.f, a2 = 0.f, a3 = 0.f;
        for (int kk = 0; kk < 64; kk += 4) {
            const float4 q4 = *(const float4*)&qs[g][kb + kk];
            float4 w;
            w = *(const float4*)&Wa[(kb + kk + 0) * 32 + j0];
            a0 = fmaf(q4.x, w.x, a0); a1 = fmaf(q4.x, w.y, a1);
            a2 = fmaf(q4.x, w.z, a2); a3 = fmaf(q4.x, w.w, a3);
            w = *(const float4*)&Wa[(kb + kk + 1) * 32 + j0];
            a0 = fmaf(q4.y, w.x, a0); a1 = fmaf(q4.y, w.y, a1);
            a2 = fmaf(q4.y, w.z, a2); a3 = fmaf(q4.y, w.w, a3);
            w = *(const float4*)&Wa[(kb + kk + 2) * 32 + j0];
            a0 = fmaf(q4.z, w.x, a0); a1 = fmaf(q4.z, w.y, a1);
            a2 = fmaf(q4.z, w.z, a2); a3 = fmaf(q4.z, w.w, a3);
            w = *(const float4*)&Wa[(kb + kk + 3) * 32 + j0];
            a0 = fmaf(q4.w, w.x, a0); a1 = fmaf(q4.w, w.y, a1);
            a2 = fmaf(q4.w, w.z, a2); a3 = fmaf(q4.w, w.w, a3);
        }
        a0 += __shfl_xor(a0, 1); a1 += __shfl_xor(a1, 1);
        a2 += __shfl_xor(a2, 1); a3 += __shfl_xor(a3, 1);
        const float4 b4 = *(const float4*)&ba[j0];
        a0 += b4.x; a1 += b4.y; a2 += b4.z; a3 += b4.w;
        // softmax over the 8 points of head (j0>>3): partner j-quad at i^2 (parity-safe)
        float m4 = fmaxf(fmaxf(a0, a1), fmaxf(a2, a3));
        const float m8 = fmaxf(m4, __shfl_xor(m4, 2));
        const float e0 = expf(a0 - m8), e1 = expf(a1 - m8);
        const float e2 = expf(a2 - m8), e3 = expf(a3 - m8);
        float s4 = e0 + e1 + e2 + e3;
        const float s8 = s4 + __shfl_xor(s4, 2);
        if (kh == 0) {
            const float rs = 1.f / s8;
            float4 r; r.x = e0 * rs; r.y = e1 * rs; r.z = e2 * rs; r.w = e3 * rs;
            *(float4*)&s_attw[g][j0] = r;
        }
    }
    __syncthreads();

    // ---- phase 1b: per-(g,s,p,h) packed pixel pairs + bf16 weights
    for (int i = t; i < G_Q * NENT; i += 256) {
        const int g = i / NENT;
        const int e = i - g * NENT;      // e in [0,192)
        const int s = e >> 5;
        const int rem = e & 31;          // p*4 + h
        const int p = rem >> 2, h = rem & 3;
        const int hp = h * P_DIM + p;
        const int d = p & 3;
        const int n = n0 + g;

        const float aw = s_attw[g][hp];
        const float offx = s_offr[g][hp * 2 + 0] / (float)WF;
        const float offy = s_offr[g][hp * 2 + 1] / (float)HF;
        const float refx = refpts[(((size_t)s * N_DIM + n) * 4 + d) * 2 + 0];
        const float refy = refpts[(((size_t)s * N_DIM + n) * 4 + d) * 2 + 1];

        const float x = (refx + offx) * (float)WF - 0.5f;
        const float y = (refy + offy) * (float)HF - 0.5f;
        const float x0f = floorf(x), y0f = floorf(y);
        const float lx = x - x0f, ly = y - y0f;
        const int x0 = (int)x0f, y0 = (int)y0f;
        const int x1 = x0 + 1, y1 = y0 + 1;

        const bool vx0 = (x0 >= 0) & (x0 < WF);
        const bool vx1 = (x1 >= 0) & (x1 < WF);
        const bool vy0 = (y0 >= 0) & (y0 < HF);
        const bool vy1 = (y1 >= 0) & (y1 < HF);

        const unsigned cx0 = (unsigned)min(max(x0, 0), WF - 1);
        const unsigned cx1 = (unsigned)min(max(x1, 0), WF - 1);
        const unsigned cy0 = (unsigned)min(max(y0, 0), HF - 1);
        const unsigned cy1 = (unsigned)min(max(y1, 0), HF - 1);

        const unsigned p00 = cy0 * WF + cx0;
        const unsigned p10 = cy0 * WF + cx1;
        const unsigned p01 = cy1 * WF + cx0;
        const unsigned p11 = cy1 * WF + cx1;
        s_pixd[g][s][p][h] = make_uint2(p00 | (p10 << 16), p01 | (p11 << 16));

        const float wx0 = 1.f - lx, wy0 = 1.f - ly;
        const float w00 = (vx0 & vy0) ? wx0 * wy0 * aw : 0.f;
        const float w10 = (vx1 & vy0) ? lx  * wy0 * aw : 0.f;
        const float w01 = (vx0 & vy1) ? wx0 * ly  * aw : 0.f;
        const float w11 = (vx1 & vy1) ? lx  * ly  * aw : 0.f;
        s_wbd[g][s][p][h] = make_uint2(
            (unsigned)f2bf(w00) | ((unsigned)f2bf(w10) << 16),
            (unsigned)f2bf(w01) | ((unsigned)f2bf(w11) << 16));
    }
    __syncthreads();

    // ---- phase 2: gather — wave = 1 query, 16 lanes/head, 2 dh per lane
    {
        const char* vb = (const char*)vhw;
        const int g = t >> 6;
        const int lane = t & 63;
        const int h = lane >> 4;
        const int dhp4 = (lane & 15) * 4;   // byte offset of the dh pair
        float accx = 0.f, accy = 0.f;

        for (int s = 0; s < S_DIM; ++s) {
            if (!s_mask[g][s]) continue;
            const char* vbs = vb + (((s * H_DIM + h) * M_DIM) * (DH * 2) + dhp4);
#pragma unroll
            for (int pg = 0; pg < 4; ++pg) {   // 2 points per iter
                const uint2 pa = s_pixd[g][s][pg * 2 + 0][h];
                const uint2 pb = s_pixd[g][s][pg * 2 + 1][h];
                const unsigned u0 = *(const unsigned*)(vbs + ((pa.x <<  6) & 0x3fffc0u));
                const unsigned u1 = *(const unsigned*)(vbs + ((pa.x >> 10) & 0x3fffc0u));
                const unsigned u2 = *(const unsigned*)(vbs + ((pa.y <<  6) & 0x3fffc0u));
                const unsigned u3 = *(const unsigned*)(vbs + ((pa.y >> 10) & 0x3fffc0u));
                const unsigned u4 = *(const unsigned*)(vbs + ((pb.x <<  6) & 0x3fffc0u));
                const unsigned u5 = *(const unsigned*)(vbs + ((pb.x >> 10) & 0x3fffc0u));
                const unsigned u6 = *(const unsigned*)(vbs + ((pb.y <<  6) & 0x3fffc0u));
                const unsigned u7 = *(const unsigned*)(vbs + ((pb.y >> 10) & 0x3fffc0u));
                const uint2 wa = s_wbd[g][s][pg * 2 + 0][h];
                const uint2 wb2 = s_wbd[g][s][pg * 2 + 1][h];
                const float w00 = bfl(wa.x),  w10 = bfh(wa.x);
                const float w01 = bfl(wa.y),  w11 = bfh(wa.y);
                const float x00 = bfl(wb2.x), x10 = bfh(wb2.x);
                const float x01 = bfl(wb2.y), x11 = bfh(wb2.y);
                accx = fmaf(w00, bfl(u0), accx); accy = fmaf(w00, bfh(u0), accy);
                accx = fmaf(w10, bfl(u1), accx); accy = fmaf(w10, bfh(u1), accy);
                accx = fmaf(w01, bfl(u2), accx); accy = fmaf(w01, bfh(u2), accy);
                accx = fmaf(w11, bfl(u3), accx); accy = fmaf(w11, bfh(u3), accy);
                accx = fmaf(x00, bfl(u4), accx); accy = fmaf(x00, bfh(u4), accy);
                accx = fmaf(x10, bfl(u5), accx); accy = fmaf(x10, bfh(u5), accy);
                accx = fmaf(x01, bfl(u6), accx); accy = fmaf(x01, bfh(u6), accy);
                accx = fmaf(x11, bfl(u7), accx); accy = fmaf(x11, bfh(u7), accy);
            }
        }
        const float inv = s_inv[g];
        *(float2*)&s_slots[g][h * 32 + (lane & 15) * 2] =
            make_float2(accx * inv, accy * inv);
    }
    __syncthreads();

    // ---- phase 3: out projection + bias + residual (Wp read 2x/block)
    {
        const int c = t & 127, half = t >> 7;
        const int g0 = half * 2;
        float a0 = 0.f, a1 = 0.f;
        for (int k = 0; k < C_DIM; k += 4) {
            const float4 s0 = *(const float4*)&s_slots[g0][k];
            const float4 s1 = *(const float4*)&s_slots[g0 + 1][k];
            const float w0 = Wp[(k + 0) * C_DIM + c];
            const float w1 = Wp[(k + 1) * C_DIM + c];
            const float w2 = Wp[(k + 2) * C_DIM + c];
            const float w3 = Wp[(k + 3) * C_DIM + c];
            a0 = fmaf(s0.x, w0, a0); a1 = fmaf(s1.x, w0, a1);
            a0 = fmaf(s0.y, w1, a0); a1 = fmaf(s1.y, w1, a1);
            a0 = fmaf(s0.z, w2, a0); a1 = fmaf(s1.z, w2, a1);
            a0 = fmaf(s0.w, w3, a0); a1 = fmaf(s1.w, w3, a1);
        }
        const int na = n0 + g0;
        const float bb = bp[c];
        out[(size_t)na * C_DIM + c]       = a0 + bb + query[(size_t)na * C_DIM + c];
        out[(size_t)(na + 1) * C_DIM + c] = a1 + bb + query[(size_t)(na + 1) * C_DIM + c];
    }
}

// ---------------------------------------------------------------- launch
extern "C" void kernel_launch(void* const* d_in, const int* in_sizes, int n_in,
                              void* d_out, int out_size, void* d_ws, size_t ws_size,
                              hipStream_t stream) {
    const float* query     = (const float*)d_in[0];
    // d_in[1] = key (unused by reference)
    const float* value     = (const float*)d_in[2];
    const float* query_pos = (const float*)d_in[3];
    const float* refpts    = (const float*)d_in[4];
    const float* Wv        = (const float*)d_in[5];
    const float* bv        = (const float*)d_in[6];
    const float* Wo        = (const float*)d_in[7];
    const float* bo        = (const float*)d_in[8];
    const float* Wa        = (const float*)d_in[9];
    const float* ba        = (const float*)d_in[10];
    const float* Wp        = (const float*)d_in[11];
    const float* bp        = (const float*)d_in[12];
    const void*  sshapes   = d_in[13];
    const void*  bev_mask  = d_in[14];

    unsigned short* vhw = (unsigned short*)d_ws;
    float* outp = (float*)d_out;

    hipLaunchKernelGGL(vproj_kernel, dim3((S_DIM * M_DIM) / 32), dim3(256), 0, stream,
                       value, Wv, bv, vhw);
    hipLaunchKernelGGL(attn_kernel, dim3(N_DIM / G_Q), dim3(256), 0, stream,
                       vhw, query, query_pos, Wo, bo, Wa, ba,
                       refpts, bev_mask, sshapes, Wp, bp, outp);
}

// Round 12
// 82.863 us; speedup vs baseline: 1.1920x; 1.0678x over previous
//
#include <hip/hip_runtime.h>

// SpatialCrossAttention (BEVFormer) — 2 kernels:
//  A) vproj : value @ Wv + bv -> vhw bf16 (register-tiled 32-row GEMM)
//  B) attn  : R8 structure (256 thr, G_Q=4, 18.4KB LDS), phase 2 made branch-free:
//             camera mask folded into bilinear weights, 6-camera loop fully
//             unrolled -> 48 independent gather loads in flight.

#define S_DIM 6
#define N_DIM 10000
#define C_DIM 128
#define M_DIM 3680
#define H_DIM 4
#define P_DIM 8
#define DH    32
#define HF    46
#define WF    80

#define G_Q   4
#define NENT  (S_DIM * P_DIM * H_DIM)             // 192
#define VHW_SHORTS (S_DIM * H_DIM * M_DIM * DH)   // 2,826,240

__device__ __forceinline__ float bfl(unsigned u) { return __uint_as_float(u << 16); }
__device__ __forceinline__ float bfh(unsigned u) { return __uint_as_float(u & 0xffff0000u); }
__device__ __forceinline__ unsigned short f2bf(float f) {
    unsigned b = __float_as_uint(f);
    b += 0x7FFFu + ((b >> 16) & 1u);   // RNE
    return (unsigned short)(b >> 16);
}

// ---------------------------------------------------------------- kernel A
// 32 rows/block, 256 threads: thread tile = 4 rows x 4 cols.
__global__ __launch_bounds__(256) void vproj_kernel(
    const float* __restrict__ value,   // (S*M, C)
    const float* __restrict__ Wv,      // (C, C)
    const float* __restrict__ bv,      // (C)
    unsigned short* __restrict__ vhw)  // (S, H, M, DH) bf16
{
    const int row0 = blockIdx.x * 32;
    const int t = threadIdx.x;
    const int tc = t & 31, tr = t >> 5;   // tr in [0,8)
    const int c0 = tc * 4, r0 = tr * 4;
    __shared__ float vs[32][C_DIM];       // 16 KB

    for (int i = t; i < 32 * 32; i += 256) {
        const int row = i >> 5, c4 = (i & 31) * 4;
        *(float4*)&vs[row][c4] =
            *(const float4*)&value[(size_t)(row0 + row) * C_DIM + c4];
    }
    __syncthreads();

    float acc[4][4];
#pragma unroll
    for (int r = 0; r < 4; ++r)
#pragma unroll
        for (int c = 0; c < 4; ++c) acc[r][c] = 0.f;

    for (int k = 0; k < C_DIM; k += 4) {
        const float4 w0 = *(const float4*)&Wv[(k + 0) * C_DIM + c0];
        const float4 w1 = *(const float4*)&Wv[(k + 1) * C_DIM + c0];
        const float4 w2 = *(const float4*)&Wv[(k + 2) * C_DIM + c0];
        const float4 w3 = *(const float4*)&Wv[(k + 3) * C_DIM + c0];
#pragma unroll
        for (int r = 0; r < 4; ++r) {
            const float4 v = *(const float4*)&vs[r0 + r][k];
            acc[r][0] = fmaf(v.x, w0.x, acc[r][0]);
            acc[r][0] = fmaf(v.y, w1.x, acc[r][0]);
            acc[r][0] = fmaf(v.z, w2.x, acc[r][0]);
            acc[r][0] = fmaf(v.w, w3.x, acc[r][0]);
            acc[r][1] = fmaf(v.x, w0.y, acc[r][1]);
            acc[r][1] = fmaf(v.y, w1.y, acc[r][1]);
            acc[r][1] = fmaf(v.z, w2.y, acc[r][1]);
            acc[r][1] = fmaf(v.w, w3.y, acc[r][1]);
            acc[r][2] = fmaf(v.x, w0.z, acc[r][2]);
            acc[r][2] = fmaf(v.y, w1.z, acc[r][2]);
            acc[r][2] = fmaf(v.z, w2.z, acc[r][2]);
            acc[r][2] = fmaf(v.w, w3.z, acc[r][2]);
            acc[r][3] = fmaf(v.x, w0.w, acc[r][3]);
            acc[r][3] = fmaf(v.y, w1.w, acc[r][3]);
            acc[r][3] = fmaf(v.z, w2.w, acc[r][3]);
            acc[r][3] = fmaf(v.w, w3.w, acc[r][3]);
        }
    }

    const float4 bb = *(const float4*)&bv[c0];
    const int h = c0 >> 5, dh0 = c0 & 31;
#pragma unroll
    for (int r = 0; r < 4; ++r) {
        const int row = row0 + r0 + r;
        const int s = row / M_DIM, m = row - s * M_DIM;
        ushort4 o;
        o.x = f2bf(acc[r][0] + bb.x);
        o.y = f2bf(acc[r][1] + bb.y);
        o.z = f2bf(acc[r][2] + bb.z);
        o.w = f2bf(acc[r][3] + bb.w);
        *(ushort4*)&vhw[(((size_t)s * H_DIM + h) * M_DIM + m) * DH + dh0] = o;
    }
}

// ---------------------------------------------------------------- kernel B
__global__ __launch_bounds__(256, 4) void attn_kernel(
    const unsigned short* __restrict__ vhw,   // (S,H,M,DH) bf16
    const float* __restrict__ query,
    const float* __restrict__ query_pos,
    const float* __restrict__ Wo, const float* __restrict__ bo,   // (C,64),(64)
    const float* __restrict__ Wa, const float* __restrict__ ba,   // (C,32),(32)
    const float* __restrict__ refpts,   // (S,1,N,4,2)
    const void* __restrict__ bev_mask,  // (S,1,N,4) bool/int32
    const void* __restrict__ sshapes,   // int probe
    const float* __restrict__ Wp, const float* __restrict__ bp,
    float* __restrict__ out)            // (1,N,C)
{
    const int n0 = blockIdx.x * G_Q;
    const int t = threadIdx.x;          // 256

    __shared__ float  qs[G_Q][C_DIM];                     // 2 KB
    __shared__ float  s_offr[G_Q][64];                    // 1 KB
    __shared__ float  s_attw[G_Q][32];                    // 0.5 KB
    __shared__ uint2  s_pixd[G_Q][S_DIM][P_DIM][H_DIM];   // 6 KB (c00|c10, c01|c11)
    __shared__ uint2  s_wbd[G_Q][S_DIM][P_DIM][H_DIM];    // 6 KB (bf16 w00|w10, w01|w11)
    __shared__ float  s_slots[G_Q][C_DIM];                // 2 KB
    __shared__ int    s_mask[G_Q][S_DIM];
    __shared__ float  s_inv[G_Q];

    // ---- phase 0: queries + masks
    for (int i = t; i < G_Q * C_DIM; i += 256) {
        const int g = i >> 7, c = i & 127;
        const size_t a = (size_t)(n0 + g) * C_DIM + c;
        qs[g][c] = query[a] + query_pos[a];
    }
    if (t < G_Q * S_DIM) {   // 24
        const int g = t / S_DIM, s = t - g * S_DIM;
        const int n = n0 + g;
        const int* ss32 = (const int*)sshapes;
        const bool i32mode = (ss32[1] == WF);
        int mk;
        if (i32mode) {
            const int* bm = (const int*)bev_mask + ((size_t)s * N_DIM + n) * 4;
            mk = (bm[0] | bm[1] | bm[2] | bm[3]) ? 1 : 0;
        } else {
            const unsigned char* bm =
                (const unsigned char*)bev_mask + ((size_t)s * N_DIM + n) * 4;
            mk = (bm[0] | bm[1] | bm[2] | bm[3]) ? 1 : 0;
        }
        s_mask[g][s] = mk;
    }
    __syncthreads();
    if (t < G_Q) {
        int c = 0;
#pragma unroll
        for (int s = 0; s < S_DIM; ++s) c += s_mask[t][s];
        s_inv[t] = 1.f / fmaxf((float)c, 1.f);
    }

    // ---- phase 1: fused qproj (R8 form: qs reads are wave-uniform broadcasts)
    {
        const int g = t >> 6, j = t & 63;
        float acc = 0.f;
        for (int k = 0; k < C_DIM; k += 4) {
            const float4 q4 = *(const float4*)&qs[g][k];
            acc = fmaf(q4.x, Wo[(k + 0) * 64 + j], acc);
            acc = fmaf(q4.y, Wo[(k + 1) * 64 + j], acc);
            acc = fmaf(q4.z, Wo[(k + 2) * 64 + j], acc);
            acc = fmaf(q4.w, Wo[(k + 3) * 64 + j], acc);
        }
        s_offr[g][j] = acc + bo[j];
    }
    if (t < G_Q * 32) {   // logit + softmax in-register (shfl, no barrier needed)
        const int g = t >> 5, jj = t & 31;
        float ar = 0.f;
        for (int k = 0; k < C_DIM; k += 4) {
            const float4 q4 = *(const float4*)&qs[g][k];
            ar = fmaf(q4.x, Wa[(k + 0) * 32 + jj], ar);
            ar = fmaf(q4.y, Wa[(k + 1) * 32 + jj], ar);
            ar = fmaf(q4.z, Wa[(k + 2) * 32 + jj], ar);
            ar = fmaf(q4.w, Wa[(k + 3) * 32 + jj], ar);
        }
        ar += ba[jj];
        float m = ar;
        for (int d = 1; d < 8; d <<= 1) m = fmaxf(m, __shfl_xor(m, d, 8));
        const float e = expf(ar - m);
        float sum = e;
        for (int d = 1; d < 8; d <<= 1) sum += __shfl_xor(sum, d, 8);
        s_attw[g][jj] = e / sum;
    }
    __syncthreads();

    // ---- phase 1b: packed pixel pairs + bf16 weights; camera mask folded in
    for (int i = t; i < G_Q * NENT; i += 256) {
        const int g = i / NENT;
        const int e = i - g * NENT;      // e in [0,192)
        const int s = e >> 5;
        const int rem = e & 31;          // p*4 + h
        const int p = rem >> 2, h = rem & 3;
        const int hp = h * P_DIM + p;
        const int d = p & 3;
        const int n = n0 + g;

        // mask folded into weights: masked camera contributes exactly 0,
        // clamped pixel addresses stay in-bounds -> phase 2 can be branch-free
        const float aw = s_attw[g][hp] * (float)s_mask[g][s];
        const float offx = s_offr[g][hp * 2 + 0] / (float)WF;
        const float offy = s_offr[g][hp * 2 + 1] / (float)HF;
        const float refx = refpts[(((size_t)s * N_DIM + n) * 4 + d) * 2 + 0];
        const float refy = refpts[(((size_t)s * N_DIM + n) * 4 + d) * 2 + 1];

        const float x = (refx + offx) * (float)WF - 0.5f;
        const float y = (refy + offy) * (float)HF - 0.5f;
        const float x0f = floorf(x), y0f = floorf(y);
        const float lx = x - x0f, ly = y - y0f;
        const int x0 = (int)x0f, y0 = (int)y0f;
        const int x1 = x0 + 1, y1 = y0 + 1;

        const bool vx0 = (x0 >= 0) & (x0 < WF);
        const bool vx1 = (x1 >= 0) & (x1 < WF);
        const bool vy0 = (y0 >= 0) & (y0 < HF);
        const bool vy1 = (y1 >= 0) & (y1 < HF);

        const unsigned cx0 = (unsigned)min(max(x0, 0), WF - 1);
        const unsigned cx1 = (unsigned)min(max(x1, 0), WF - 1);
        const unsigned cy0 = (unsigned)min(max(y0, 0), HF - 1);
        const unsigned cy1 = (unsigned)min(max(y1, 0), HF - 1);

        const unsigned p00 = cy0 * WF + cx0;
        const unsigned p10 = cy0 * WF + cx1;
        const unsigned p01 = cy1 * WF + cx0;
        const unsigned p11 = cy1 * WF + cx1;
        s_pixd[g][s][p][h] = make_uint2(p00 | (p10 << 16), p01 | (p11 << 16));

        const float wx0 = 1.f - lx, wy0 = 1.f - ly;
        const float w00 = (vx0 & vy0) ? wx0 * wy0 * aw : 0.f;
        const float w10 = (vx1 & vy0) ? lx  * wy0 * aw : 0.f;
        const float w01 = (vx0 & vy1) ? wx0 * ly  * aw : 0.f;
        const float w11 = (vx1 & vy1) ? lx  * ly  * aw : 0.f;
        s_wbd[g][s][p][h] = make_uint2(
            (unsigned)f2bf(w00) | ((unsigned)f2bf(w10) << 16),
            (unsigned)f2bf(w01) | ((unsigned)f2bf(w11) << 16));
    }
    __syncthreads();

    // ---- phase 2: gather — branch-free, all 6 cameras unrolled.
    //      wave = 1 query, 16 lanes/head, 2 dh per lane.
    {
        const char* vb = (const char*)vhw;
        const int g = t >> 6;
        const int lane = t & 63;
        const int h = lane >> 4;
        const int dhp4 = (lane & 15) * 4;   // byte offset of the dh pair
        float accx = 0.f, accy = 0.f;

#pragma unroll
        for (int s = 0; s < S_DIM; ++s) {
            const char* vbs = vb + (((s * H_DIM + h) * M_DIM) * (DH * 2) + dhp4);
#pragma unroll
            for (int pg = 0; pg < 4; ++pg) {   // 2 points per iter
                const uint2 pa = s_pixd[g][s][pg * 2 + 0][h];
                const uint2 pb = s_pixd[g][s][pg * 2 + 1][h];
                const unsigned u0 = *(const unsigned*)(vbs + ((pa.x <<  6) & 0x3fffc0u));
                const unsigned u1 = *(const unsigned*)(vbs + ((pa.x >> 10) & 0x3fffc0u));
                const unsigned u2 = *(const unsigned*)(vbs + ((pa.y <<  6) & 0x3fffc0u));
                const unsigned u3 = *(const unsigned*)(vbs + ((pa.y >> 10) & 0x3fffc0u));
                const unsigned u4 = *(const unsigned*)(vbs + ((pb.x <<  6) & 0x3fffc0u));
                const unsigned u5 = *(const unsigned*)(vbs + ((pb.x >> 10) & 0x3fffc0u));
                const unsigned u6 = *(const unsigned*)(vbs + ((pb.y <<  6) & 0x3fffc0u));
                const unsigned u7 = *(const unsigned*)(vbs + ((pb.y >> 10) & 0x3fffc0u));
                const uint2 wa = s_wbd[g][s][pg * 2 + 0][h];
                const uint2 wb2 = s_wbd[g][s][pg * 2 + 1][h];
                const float w00 = bfl(wa.x),  w10 = bfh(wa.x);
                const float w01 = bfl(wa.y),  w11 = bfh(wa.y);
                const float x00 = bfl(wb2.x), x10 = bfh(wb2.x);
                const float x01 = bfl(wb2.y), x11 = bfh(wb2.y);
                accx = fmaf(w00, bfl(u0), accx); accy = fmaf(w00, bfh(u0), accy);
                accx = fmaf(w10, bfl(u1), accx); accy = fmaf(w10, bfh(u1), accy);
                accx = fmaf(w01, bfl(u2), accx); accy = fmaf(w01, bfh(u2), accy);
                accx = fmaf(w11, bfl(u3), accx); accy = fmaf(w11, bfh(u3), accy);
                accx = fmaf(x00, bfl(u4), accx); accy = fmaf(x00, bfh(u4), accy);
                accx = fmaf(x10, bfl(u5), accx); accy = fmaf(x10, bfh(u5), accy);
                accx = fmaf(x01, bfl(u6), accx); accy = fmaf(x01, bfh(u6), accy);
                accx = fmaf(x11, bfl(u7), accx); accy = fmaf(x11, bfh(u7), accy);
            }
        }
        const float inv = s_inv[g];
        *(float2*)&s_slots[g][h * 32 + (lane & 15) * 2] =
            make_float2(accx * inv, accy * inv);
    }
    __syncthreads();

    // ---- phase 3: out projection + bias + residual (Wp read 2x/block)
    {
        const int c = t & 127, half = t >> 7;
        const int g0 = half * 2;
        float a0 = 0.f, a1 = 0.f;
        for (int k = 0; k < C_DIM; k += 4) {
            const float4 s0 = *(const float4*)&s_slots[g0][k];
            const float4 s1 = *(const float4*)&s_slots[g0 + 1][k];
            const float w0 = Wp[(k + 0) * C_DIM + c];
            const float w1 = Wp[(k + 1) * C_DIM + c];
            const float w2 = Wp[(k + 2) * C_DIM + c];
            const float w3 = Wp[(k + 3) * C_DIM + c];
            a0 = fmaf(s0.x, w0, a0); a1 = fmaf(s1.x, w0, a1);
            a0 = fmaf(s0.y, w1, a0); a1 = fmaf(s1.y, w1, a1);
            a0 = fmaf(s0.z, w2, a0); a1 = fmaf(s1.z, w2, a1);
            a0 = fmaf(s0.w, w3, a0); a1 = fmaf(s1.w, w3, a1);
        }
        const int na = n0 + g0;
        const float bb = bp[c];
        out[(size_t)na * C_DIM + c]       = a0 + bb + query[(size_t)na * C_DIM + c];
        out[(size_t)(na + 1) * C_DIM + c] = a1 + bb + query[(size_t)(na + 1) * C_DIM + c];
    }
}

// ---------------------------------------------------------------- launch
extern "C" void kernel_launch(void* const* d_in, const int* in_sizes, int n_in,
                              void* d_out, int out_size, void* d_ws, size_t ws_size,
                              hipStream_t stream) {
    const float* query     = (const float*)d_in[0];
    // d_in[1] = key (unused by reference)
    const float* value     = (const float*)d_in[2];
    const float* query_pos = (const float*)d_in[3];
    const float* refpts    = (const float*)d_in[4];
    const float* Wv        = (const float*)d_in[5];
    const float* bv        = (const float*)d_in[6];
    const float* Wo        = (const float*)d_in[7];
    const float* bo        = (const float*)d_in[8];
    const float* Wa        = (const float*)d_in[9];
    const float* ba        = (const float*)d_in[10];
    const float* Wp        = (const float*)d_in[11];
    const float* bp        = (const float*)d_in[12];
    const void*  sshapes   = d_in[13];
    const void*  bev_mask  = d_in[14];

    unsigned short* vhw = (unsigned short*)d_ws;
    float* outp = (float*)d_out;

    hipLaunchKernelGGL(vproj_kernel, dim3((S_DIM * M_DIM) / 32), dim3(256), 0, stream,
                       value, Wv, bv, vhw);
    hipLaunchKernelGGL(attn_kernel, dim3(N_DIM / G_Q), dim3(256), 0, stream,
                       vhw, query, query_pos, Wo, bo, Wa, ba,
                       refpts, bev_mask, sshapes, Wp, bp, outp);
}

// Round 13
// 81.624 us; speedup vs baseline: 1.2101x; 1.0152x over previous
//
#include <hip/hip_runtime.h>

// SpatialCrossAttention (BEVFormer) — 2 kernels:
//  A) vproj : value @ Wv + bv -> vhw bf16 (register-tiled 32-row GEMM)
//  B) attn  : R8 structure (256 thr, G_Q=4, 18.4KB LDS); phase 2 uses dwordx2
//             gather with point-parity lanes (8 lanes x 2 points per head):
//             VMEM instructions halved, ~20% fewer issue slots per MAC.

#define S_DIM 6
#define N_DIM 10000
#define C_DIM 128
#define M_DIM 3680
#define H_DIM 4
#define P_DIM 8
#define DH    32
#define HF    46
#define WF    80

#define G_Q   4
#define NENT  (S_DIM * P_DIM * H_DIM)             // 192
#define VHW_SHORTS (S_DIM * H_DIM * M_DIM * DH)   // 2,826,240

__device__ __forceinline__ float bfl(unsigned u) { return __uint_as_float(u << 16); }
__device__ __forceinline__ float bfh(unsigned u) { return __uint_as_float(u & 0xffff0000u); }
__device__ __forceinline__ unsigned short f2bf(float f) {
    unsigned b = __float_as_uint(f);
    b += 0x7FFFu + ((b >> 16) & 1u);   // RNE
    return (unsigned short)(b >> 16);
}

// ---------------------------------------------------------------- kernel A
// 32 rows/block, 256 threads: thread tile = 4 rows x 4 cols.
__global__ __launch_bounds__(256) void vproj_kernel(
    const float* __restrict__ value,   // (S*M, C)
    const float* __restrict__ Wv,      // (C, C)
    const float* __restrict__ bv,      // (C)
    unsigned short* __restrict__ vhw)  // (S, H, M, DH) bf16
{
    const int row0 = blockIdx.x * 32;
    const int t = threadIdx.x;
    const int tc = t & 31, tr = t >> 5;   // tr in [0,8)
    const int c0 = tc * 4, r0 = tr * 4;
    __shared__ float vs[32][C_DIM];       // 16 KB

    for (int i = t; i < 32 * 32; i += 256) {
        const int row = i >> 5, c4 = (i & 31) * 4;
        *(float4*)&vs[row][c4] =
            *(const float4*)&value[(size_t)(row0 + row) * C_DIM + c4];
    }
    __syncthreads();

    float acc[4][4];
#pragma unroll
    for (int r = 0; r < 4; ++r)
#pragma unroll
        for (int c = 0; c < 4; ++c) acc[r][c] = 0.f;

    for (int k = 0; k < C_DIM; k += 4) {
        const float4 w0 = *(const float4*)&Wv[(k + 0) * C_DIM + c0];
        const float4 w1 = *(const float4*)&Wv[(k + 1) * C_DIM + c0];
        const float4 w2 = *(const float4*)&Wv[(k + 2) * C_DIM + c0];
        const float4 w3 = *(const float4*)&Wv[(k + 3) * C_DIM + c0];
#pragma unroll
        for (int r = 0; r < 4; ++r) {
            const float4 v = *(const float4*)&vs[r0 + r][k];
            acc[r][0] = fmaf(v.x, w0.x, acc[r][0]);
            acc[r][0] = fmaf(v.y, w1.x, acc[r][0]);
            acc[r][0] = fmaf(v.z, w2.x, acc[r][0]);
            acc[r][0] = fmaf(v.w, w3.x, acc[r][0]);
            acc[r][1] = fmaf(v.x, w0.y, acc[r][1]);
            acc[r][1] = fmaf(v.y, w1.y, acc[r][1]);
            acc[r][1] = fmaf(v.z, w2.y, acc[r][1]);
            acc[r][1] = fmaf(v.w, w3.y, acc[r][1]);
            acc[r][2] = fmaf(v.x, w0.z, acc[r][2]);
            acc[r][2] = fmaf(v.y, w1.z, acc[r][2]);
            acc[r][2] = fmaf(v.z, w2.z, acc[r][2]);
            acc[r][2] = fmaf(v.w, w3.z, acc[r][2]);
            acc[r][3] = fmaf(v.x, w0.w, acc[r][3]);
            acc[r][3] = fmaf(v.y, w1.w, acc[r][3]);
            acc[r][3] = fmaf(v.z, w2.w, acc[r][3]);
            acc[r][3] = fmaf(v.w, w3.w, acc[r][3]);
        }
    }

    const float4 bb = *(const float4*)&bv[c0];
    const int h = c0 >> 5, dh0 = c0 & 31;
#pragma unroll
    for (int r = 0; r < 4; ++r) {
        const int row = row0 + r0 + r;
        const int s = row / M_DIM, m = row - s * M_DIM;
        ushort4 o;
        o.x = f2bf(acc[r][0] + bb.x);
        o.y = f2bf(acc[r][1] + bb.y);
        o.z = f2bf(acc[r][2] + bb.z);
        o.w = f2bf(acc[r][3] + bb.w);
        *(ushort4*)&vhw[(((size_t)s * H_DIM + h) * M_DIM + m) * DH + dh0] = o;
    }
}

// ---------------------------------------------------------------- kernel B
__global__ __launch_bounds__(256, 4) void attn_kernel(
    const unsigned short* __restrict__ vhw,   // (S,H,M,DH) bf16
    const float* __restrict__ query,
    const float* __restrict__ query_pos,
    const float* __restrict__ Wo, const float* __restrict__ bo,   // (C,64),(64)
    const float* __restrict__ Wa, const float* __restrict__ ba,   // (C,32),(32)
    const float* __restrict__ refpts,   // (S,1,N,4,2)
    const void* __restrict__ bev_mask,  // (S,1,N,4) bool/int32
    const void* __restrict__ sshapes,   // int probe
    const float* __restrict__ Wp, const float* __restrict__ bp,
    float* __restrict__ out)            // (1,N,C)
{
    const int n0 = blockIdx.x * G_Q;
    const int t = threadIdx.x;          // 256

    __shared__ float  qs[G_Q][C_DIM];                     // 2 KB
    __shared__ float  s_offr[G_Q][64];                    // 1 KB
    __shared__ float  s_attw[G_Q][32];                    // 0.5 KB
    __shared__ uint2  s_pixd[G_Q][S_DIM][P_DIM][H_DIM];   // 6 KB (c00|c10, c01|c11)
    __shared__ uint2  s_wbd[G_Q][S_DIM][P_DIM][H_DIM];    // 6 KB (bf16 w00|w10, w01|w11)
    __shared__ float  s_slots[G_Q][C_DIM];                // 2 KB
    __shared__ int    s_mask[G_Q][S_DIM];
    __shared__ float  s_inv[G_Q];

    // ---- phase 0: queries + masks
    for (int i = t; i < G_Q * C_DIM; i += 256) {
        const int g = i >> 7, c = i & 127;
        const size_t a = (size_t)(n0 + g) * C_DIM + c;
        qs[g][c] = query[a] + query_pos[a];
    }
    if (t < G_Q * S_DIM) {   // 24
        const int g = t / S_DIM, s = t - g * S_DIM;
        const int n = n0 + g;
        const int* ss32 = (const int*)sshapes;
        const bool i32mode = (ss32[1] == WF);
        int mk;
        if (i32mode) {
            const int* bm = (const int*)bev_mask + ((size_t)s * N_DIM + n) * 4;
            mk = (bm[0] | bm[1] | bm[2] | bm[3]) ? 1 : 0;
        } else {
            const unsigned char* bm =
                (const unsigned char*)bev_mask + ((size_t)s * N_DIM + n) * 4;
            mk = (bm[0] | bm[1] | bm[2] | bm[3]) ? 1 : 0;
        }
        s_mask[g][s] = mk;
    }
    __syncthreads();
    if (t < G_Q) {
        int c = 0;
#pragma unroll
        for (int s = 0; s < S_DIM; ++s) c += s_mask[t][s];
        s_inv[t] = 1.f / fmaxf((float)c, 1.f);
    }

    // ---- phase 1: fused qproj (wave-uniform qs broadcasts)
    {
        const int g = t >> 6, j = t & 63;
        float acc = 0.f;
        for (int k = 0; k < C_DIM; k += 4) {
            const float4 q4 = *(const float4*)&qs[g][k];
            acc = fmaf(q4.x, Wo[(k + 0) * 64 + j], acc);
            acc = fmaf(q4.y, Wo[(k + 1) * 64 + j], acc);
            acc = fmaf(q4.z, Wo[(k + 2) * 64 + j], acc);
            acc = fmaf(q4.w, Wo[(k + 3) * 64 + j], acc);
        }
        s_offr[g][j] = acc + bo[j];
    }
    if (t < G_Q * 32) {   // logit + softmax in-register (shfl, no barrier needed)
        const int g = t >> 5, jj = t & 31;
        float ar = 0.f;
        for (int k = 0; k < C_DIM; k += 4) {
            const float4 q4 = *(const float4*)&qs[g][k];
            ar = fmaf(q4.x, Wa[(k + 0) * 32 + jj], ar);
            ar = fmaf(q4.y, Wa[(k + 1) * 32 + jj], ar);
            ar = fmaf(q4.z, Wa[(k + 2) * 32 + jj], ar);
            ar = fmaf(q4.w, Wa[(k + 3) * 32 + jj], ar);
        }
        ar += ba[jj];
        float m = ar;
        for (int d = 1; d < 8; d <<= 1) m = fmaxf(m, __shfl_xor(m, d, 8));
        const float e = expf(ar - m);
        float sum = e;
        for (int d = 1; d < 8; d <<= 1) sum += __shfl_xor(sum, d, 8);
        s_attw[g][jj] = e / sum;
    }
    __syncthreads();

    // ---- phase 1b: per-(g,s,p,h) packed pixel pairs + bf16 weights
    for (int i = t; i < G_Q * NENT; i += 256) {
        const int g = i / NENT;
        const int e = i - g * NENT;      // e in [0,192)
        const int s = e >> 5;
        const int rem = e & 31;          // p*4 + h
        const int p = rem >> 2, h = rem & 3;
        const int hp = h * P_DIM + p;
        const int d = p & 3;
        const int n = n0 + g;

        const float aw = s_attw[g][hp];
        const float offx = s_offr[g][hp * 2 + 0] / (float)WF;
        const float offy = s_offr[g][hp * 2 + 1] / (float)HF;
        const float refx = refpts[(((size_t)s * N_DIM + n) * 4 + d) * 2 + 0];
        const float refy = refpts[(((size_t)s * N_DIM + n) * 4 + d) * 2 + 1];

        const float x = (refx + offx) * (float)WF - 0.5f;
        const float y = (refy + offy) * (float)HF - 0.5f;
        const float x0f = floorf(x), y0f = floorf(y);
        const float lx = x - x0f, ly = y - y0f;
        const int x0 = (int)x0f, y0 = (int)y0f;
        const int x1 = x0 + 1, y1 = y0 + 1;

        const bool vx0 = (x0 >= 0) & (x0 < WF);
        const bool vx1 = (x1 >= 0) & (x1 < WF);
        const bool vy0 = (y0 >= 0) & (y0 < HF);
        const bool vy1 = (y1 >= 0) & (y1 < HF);

        const unsigned cx0 = (unsigned)min(max(x0, 0), WF - 1);
        const unsigned cx1 = (unsigned)min(max(x1, 0), WF - 1);
        const unsigned cy0 = (unsigned)min(max(y0, 0), HF - 1);
        const unsigned cy1 = (unsigned)min(max(y1, 0), HF - 1);

        const unsigned p00 = cy0 * WF + cx0;
        const unsigned p10 = cy0 * WF + cx1;
        const unsigned p01 = cy1 * WF + cx0;
        const unsigned p11 = cy1 * WF + cx1;
        s_pixd[g][s][p][h] = make_uint2(p00 | (p10 << 16), p01 | (p11 << 16));

        const float wx0 = 1.f - lx, wy0 = 1.f - ly;
        const float w00 = (vx0 & vy0) ? wx0 * wy0 * aw : 0.f;
        const float w10 = (vx1 & vy0) ? lx  * wy0 * aw : 0.f;
        const float w01 = (vx0 & vy1) ? wx0 * ly  * aw : 0.f;
        const float w11 = (vx1 & vy1) ? lx  * ly  * aw : 0.f;
        s_wbd[g][s][p][h] = make_uint2(
            (unsigned)f2bf(w00) | ((unsigned)f2bf(w10) << 16),
            (unsigned)f2bf(w01) | ((unsigned)f2bf(w11) << 16));
    }
    __syncthreads();

    // ---- phase 2: gather — wave = 1 query; 16 lanes/head split as
    //      8 lanes (4 dh each, dwordx2) x 2 point-parities. Combine via shfl.
    {
        const char* vb = (const char*)vhw;
        const int g = t >> 6;
        const int lane = t & 63;
        const int h = lane >> 4;
        const int sub = lane & 15;
        const int par = sub >> 3;          // point parity (0: even pts, 1: odd)
        const int dq8 = (sub & 7) * 8;     // byte offset of dh quad (4 dh)
        float a0 = 0.f, a1 = 0.f, a2 = 0.f, a3 = 0.f;

        for (int s = 0; s < S_DIM; ++s) {
            if (!s_mask[g][s]) continue;
            const char* vbs = vb + (((s * H_DIM + h) * M_DIM) * (DH * 2) + dq8);
#pragma unroll
            for (int pg = 0; pg < 4; ++pg) {   // this lane's point: pg*2+par
                const int p = pg * 2 + par;
                const uint2 pa = s_pixd[g][s][p][h];
                const uint2 wa = s_wbd[g][s][p][h];
                const uint2 u0 = *(const uint2*)(vbs + ((pa.x <<  6) & 0x3fffc0u));
                const uint2 u1 = *(const uint2*)(vbs + ((pa.x >> 10) & 0x3fffc0u));
                const uint2 u2 = *(const uint2*)(vbs + ((pa.y <<  6) & 0x3fffc0u));
                const uint2 u3 = *(const uint2*)(vbs + ((pa.y >> 10) & 0x3fffc0u));
                const float w00 = bfl(wa.x), w10 = bfh(wa.x);
                const float w01 = bfl(wa.y), w11 = bfh(wa.y);
                a0 = fmaf(w00, bfl(u0.x), a0); a1 = fmaf(w00, bfh(u0.x), a1);
                a2 = fmaf(w00, bfl(u0.y), a2); a3 = fmaf(w00, bfh(u0.y), a3);
                a0 = fmaf(w10, bfl(u1.x), a0); a1 = fmaf(w10, bfh(u1.x), a1);
                a2 = fmaf(w10, bfl(u1.y), a2); a3 = fmaf(w10, bfh(u1.y), a3);
                a0 = fmaf(w01, bfl(u2.x), a0); a1 = fmaf(w01, bfh(u2.x), a1);
                a2 = fmaf(w01, bfl(u2.y), a2); a3 = fmaf(w01, bfh(u2.y), a3);
                a0 = fmaf(w11, bfl(u3.x), a0); a1 = fmaf(w11, bfh(u3.x), a1);
                a2 = fmaf(w11, bfl(u3.y), a2); a3 = fmaf(w11, bfh(u3.y), a3);
            }
        }
        // combine point-parity partners (lane ^ 8 has the other 4 points)
        a0 += __shfl_xor(a0, 8);
        a1 += __shfl_xor(a1, 8);
        a2 += __shfl_xor(a2, 8);
        a3 += __shfl_xor(a3, 8);
        if (par == 0) {
            const float inv = s_inv[g];
            float4 r; r.x = a0 * inv; r.y = a1 * inv; r.z = a2 * inv; r.w = a3 * inv;
            *(float4*)&s_slots[g][h * 32 + (sub & 7) * 4] = r;
        }
    }
    __syncthreads();

    // ---- phase 3: out projection + bias + residual (Wp read 2x/block)
    {
        const int c = t & 127, half = t >> 7;
        const int g0 = half * 2;
        float a0 = 0.f, a1 = 0.f;
        for (int k = 0; k < C_DIM; k += 4) {
            const float4 s0 = *(const float4*)&s_slots[g0][k];
            const float4 s1 = *(const float4*)&s_slots[g0 + 1][k];
            const float w0 = Wp[(k + 0) * C_DIM + c];
            const float w1 = Wp[(k + 1) * C_DIM + c];
            const float w2 = Wp[(k + 2) * C_DIM + c];
            const float w3 = Wp[(k + 3) * C_DIM + c];
            a0 = fmaf(s0.x, w0, a0); a1 = fmaf(s1.x, w0, a1);
            a0 = fmaf(s0.y, w1, a0); a1 = fmaf(s1.y, w1, a1);
            a0 = fmaf(s0.z, w2, a0); a1 = fmaf(s1.z, w2, a1);
            a0 = fmaf(s0.w, w3, a0); a1 = fmaf(s1.w, w3, a1);
        }
        const int na = n0 + g0;
        const float bb = bp[c];
        out[(size_t)na * C_DIM + c]       = a0 + bb + query[(size_t)na * C_DIM + c];
        out[(size_t)(na + 1) * C_DIM + c] = a1 + bb + query[(size_t)(na + 1) * C_DIM + c];
    }
}

// ---------------------------------------------------------------- launch
extern "C" void kernel_launch(void* const* d_in, const int* in_sizes, int n_in,
                              void* d_out, int out_size, void* d_ws, size_t ws_size,
                              hipStream_t stream) {
    const float* query     = (const float*)d_in[0];
    // d_in[1] = key (unused by reference)
    const float* value     = (const float*)d_in[2];
    const float* query_pos = (const float*)d_in[3];
    const float* refpts    = (const float*)d_in[4];
    const float* Wv        = (const float*)d_in[5];
    const float* bv        = (const float*)d_in[6];
    const float* Wo        = (const float*)d_in[7];
    const float* bo        = (const float*)d_in[8];
    const float* Wa        = (const float*)d_in[9];
    const float* ba        = (const float*)d_in[10];
    const float* Wp        = (const float*)d_in[11];
    const float* bp        = (const float*)d_in[12];
    const void*  sshapes   = d_in[13];
    const void*  bev_mask  = d_in[14];

    unsigned short* vhw = (unsigned short*)d_ws;
    float* outp = (float*)d_out;

    hipLaunchKernelGGL(vproj_kernel, dim3((S_DIM * M_DIM) / 32), dim3(256), 0, stream,
                       value, Wv, bv, vhw);
    hipLaunchKernelGGL(attn_kernel, dim3(N_DIM / G_Q), dim3(256), 0, stream,
                       vhw, query, query_pos, Wo, bo, Wa, ba,
                       refpts, bev_mask, sshapes, Wp, bp, outp);
}

// Round 14
// 78.385 us; speedup vs baseline: 1.2601x; 1.0413x over previous
//
#include <hip/hip_runtime.h>

// SpatialCrossAttention (BEVFormer) — 2 kernels (best measured config, R8):
//  A) vproj : value @ Wv + bv -> vhw bf16 (register-tiled 32-row GEMM)
//  B) attn  : fused qproj + packed per-(g,s,p,h) precompute (8B pix + 8B bf16 w)
//             + dword-pair bf16 gather + @Wp + residual.
//  LDS ~18.5 KB; launch_bounds(256,4). Measured: attn 61.5us, total 78.3us.
//  Rounds 9-12 established: occupancy (42->60%), VMEM width (4B->8B), VALU cut
//  (-20%), branch-free unroll — all land >= this config. Structural plateau.

#define S_DIM 6
#define N_DIM 10000
#define C_DIM 128
#define M_DIM 3680
#define H_DIM 4
#define P_DIM 8
#define DH    32
#define HF    46
#define WF    80

#define G_Q   4
#define NENT  (S_DIM * P_DIM * H_DIM)             // 192
#define VHW_SHORTS (S_DIM * H_DIM * M_DIM * DH)   // 2,826,240

__device__ __forceinline__ float bfl(unsigned u) { return __uint_as_float(u << 16); }
__device__ __forceinline__ float bfh(unsigned u) { return __uint_as_float(u & 0xffff0000u); }
__device__ __forceinline__ unsigned short f2bf(float f) {
    unsigned b = __float_as_uint(f);
    b += 0x7FFFu + ((b >> 16) & 1u);   // RNE
    return (unsigned short)(b >> 16);
}

// ---------------------------------------------------------------- kernel A
// 32 rows/block, 256 threads: thread tile = 4 rows x 4 cols.
__global__ __launch_bounds__(256) void vproj_kernel(
    const float* __restrict__ value,   // (S*M, C)
    const float* __restrict__ Wv,      // (C, C)
    const float* __restrict__ bv,      // (C)
    unsigned short* __restrict__ vhw)  // (S, H, M, DH) bf16
{
    const int row0 = blockIdx.x * 32;
    const int t = threadIdx.x;
    const int tc = t & 31, tr = t >> 5;   // tr in [0,8)
    const int c0 = tc * 4, r0 = tr * 4;
    __shared__ float vs[32][C_DIM];       // 16 KB

    for (int i = t; i < 32 * 32; i += 256) {
        const int row = i >> 5, c4 = (i & 31) * 4;
        *(float4*)&vs[row][c4] =
            *(const float4*)&value[(size_t)(row0 + row) * C_DIM + c4];
    }
    __syncthreads();

    float acc[4][4];
#pragma unroll
    for (int r = 0; r < 4; ++r)
#pragma unroll
        for (int c = 0; c < 4; ++c) acc[r][c] = 0.f;

    for (int k = 0; k < C_DIM; k += 4) {
        const float4 w0 = *(const float4*)&Wv[(k + 0) * C_DIM + c0];
        const float4 w1 = *(const float4*)&Wv[(k + 1) * C_DIM + c0];
        const float4 w2 = *(const float4*)&Wv[(k + 2) * C_DIM + c0];
        const float4 w3 = *(const float4*)&Wv[(k + 3) * C_DIM + c0];
#pragma unroll
        for (int r = 0; r < 4; ++r) {
            const float4 v = *(const float4*)&vs[r0 + r][k];
            acc[r][0] = fmaf(v.x, w0.x, acc[r][0]);
            acc[r][0] = fmaf(v.y, w1.x, acc[r][0]);
            acc[r][0] = fmaf(v.z, w2.x, acc[r][0]);
            acc[r][0] = fmaf(v.w, w3.x, acc[r][0]);
            acc[r][1] = fmaf(v.x, w0.y, acc[r][1]);
            acc[r][1] = fmaf(v.y, w1.y, acc[r][1]);
            acc[r][1] = fmaf(v.z, w2.y, acc[r][1]);
            acc[r][1] = fmaf(v.w, w3.y, acc[r][1]);
            acc[r][2] = fmaf(v.x, w0.z, acc[r][2]);
            acc[r][2] = fmaf(v.y, w1.z, acc[r][2]);
            acc[r][2] = fmaf(v.z, w2.z, acc[r][2]);
            acc[r][2] = fmaf(v.w, w3.z, acc[r][2]);
            acc[r][3] = fmaf(v.x, w0.w, acc[r][3]);
            acc[r][3] = fmaf(v.y, w1.w, acc[r][3]);
            acc[r][3] = fmaf(v.z, w2.w, acc[r][3]);
            acc[r][3] = fmaf(v.w, w3.w, acc[r][3]);
        }
    }

    const float4 bb = *(const float4*)&bv[c0];
    const int h = c0 >> 5, dh0 = c0 & 31;
#pragma unroll
    for (int r = 0; r < 4; ++r) {
        const int row = row0 + r0 + r;
        const int s = row / M_DIM, m = row - s * M_DIM;
        ushort4 o;
        o.x = f2bf(acc[r][0] + bb.x);
        o.y = f2bf(acc[r][1] + bb.y);
        o.z = f2bf(acc[r][2] + bb.z);
        o.w = f2bf(acc[r][3] + bb.w);
        *(ushort4*)&vhw[(((size_t)s * H_DIM + h) * M_DIM + m) * DH + dh0] = o;
    }
}

// ---------------------------------------------------------------- kernel B
__global__ __launch_bounds__(256, 4) void attn_kernel(
    const unsigned short* __restrict__ vhw,   // (S,H,M,DH) bf16
    const float* __restrict__ query,
    const float* __restrict__ query_pos,
    const float* __restrict__ Wo, const float* __restrict__ bo,   // (C,64),(64)
    const float* __restrict__ Wa, const float* __restrict__ ba,   // (C,32),(32)
    const float* __restrict__ refpts,   // (S,1,N,4,2)
    const void* __restrict__ bev_mask,  // (S,1,N,4) bool/int32
    const void* __restrict__ sshapes,   // int probe
    const float* __restrict__ Wp, const float* __restrict__ bp,
    float* __restrict__ out)            // (1,N,C)
{
    const int n0 = blockIdx.x * G_Q;
    const int t = threadIdx.x;          // 256

    __shared__ float  qs[G_Q][C_DIM];                     // 2 KB
    __shared__ float  s_offr[G_Q][64];                    // 1 KB
    __shared__ float  s_attw[G_Q][32];                    // 0.5 KB
    __shared__ uint2  s_pixd[G_Q][S_DIM][P_DIM][H_DIM];   // 6 KB (c00|c10, c01|c11)
    __shared__ uint2  s_wbd[G_Q][S_DIM][P_DIM][H_DIM];    // 6 KB (bf16 w00|w10, w01|w11)
    __shared__ float  s_slots[G_Q][C_DIM];                // 2 KB
    __shared__ int    s_mask[G_Q][S_DIM];
    __shared__ float  s_inv[G_Q];

    // ---- phase 0: queries + masks
    for (int i = t; i < G_Q * C_DIM; i += 256) {
        const int g = i >> 7, c = i & 127;
        const size_t a = (size_t)(n0 + g) * C_DIM + c;
        qs[g][c] = query[a] + query_pos[a];
    }
    if (t < G_Q * S_DIM) {   // 24
        const int g = t / S_DIM, s = t - g * S_DIM;
        const int n = n0 + g;
        const int* ss32 = (const int*)sshapes;
        const bool i32mode = (ss32[1] == WF);
        int mk;
        if (i32mode) {
            const int* bm = (const int*)bev_mask + ((size_t)s * N_DIM + n) * 4;
            mk = (bm[0] | bm[1] | bm[2] | bm[3]) ? 1 : 0;
        } else {
            const unsigned char* bm =
                (const unsigned char*)bev_mask + ((size_t)s * N_DIM + n) * 4;
            mk = (bm[0] | bm[1] | bm[2] | bm[3]) ? 1 : 0;
        }
        s_mask[g][s] = mk;
    }
    __syncthreads();
    if (t < G_Q) {
        int c = 0;
#pragma unroll
        for (int s = 0; s < S_DIM; ++s) c += s_mask[t][s];
        s_inv[t] = 1.f / fmaxf((float)c, 1.f);
    }

    // ---- phase 1: fused qproj (offsets all threads; logits+softmax waves 0-1)
    {
        const int g = t >> 6, j = t & 63;
        float acc = 0.f;
        for (int k = 0; k < C_DIM; k += 4) {
            const float4 q4 = *(const float4*)&qs[g][k];
            acc = fmaf(q4.x, Wo[(k + 0) * 64 + j], acc);
            acc = fmaf(q4.y, Wo[(k + 1) * 64 + j], acc);
            acc = fmaf(q4.z, Wo[(k + 2) * 64 + j], acc);
            acc = fmaf(q4.w, Wo[(k + 3) * 64 + j], acc);
        }
        s_offr[g][j] = acc + bo[j];
    }
    if (t < G_Q * 32) {   // logit + softmax in-register (shfl, no barrier needed)
        const int g = t >> 5, jj = t & 31;
        float ar = 0.f;
        for (int k = 0; k < C_DIM; k += 4) {
            const float4 q4 = *(const float4*)&qs[g][k];
            ar = fmaf(q4.x, Wa[(k + 0) * 32 + jj], ar);
            ar = fmaf(q4.y, Wa[(k + 1) * 32 + jj], ar);
            ar = fmaf(q4.z, Wa[(k + 2) * 32 + jj], ar);
            ar = fmaf(q4.w, Wa[(k + 3) * 32 + jj], ar);
        }
        ar += ba[jj];
        float m = ar;
        for (int d = 1; d < 8; d <<= 1) m = fmaxf(m, __shfl_xor(m, d, 8));
        const float e = expf(ar - m);
        float sum = e;
        for (int d = 1; d < 8; d <<= 1) sum += __shfl_xor(sum, d, 8);
        s_attw[g][jj] = e / sum;
    }
    __syncthreads();

    // ---- phase 1b: per-(g,s,p,h) packed pixel pairs + bf16 weights
    for (int i = t; i < G_Q * NENT; i += 256) {
        const int g = i / NENT;
        const int e = i - g * NENT;      // e in [0,192)
        const int s = e >> 5;
        const int rem = e & 31;          // p*4 + h
        const int p = rem >> 2, h = rem & 3;
        const int hp = h * P_DIM + p;
        const int d = p & 3;
        const int n = n0 + g;

        const float aw = s_attw[g][hp];
        const float offx = s_offr[g][hp * 2 + 0] / (float)WF;
        const float offy = s_offr[g][hp * 2 + 1] / (float)HF;
        const float refx = refpts[(((size_t)s * N_DIM + n) * 4 + d) * 2 + 0];
        const float refy = refpts[(((size_t)s * N_DIM + n) * 4 + d) * 2 + 1];

        const float x = (refx + offx) * (float)WF - 0.5f;
        const float y = (refy + offy) * (float)HF - 0.5f;
        const float x0f = floorf(x), y0f = floorf(y);
        const float lx = x - x0f, ly = y - y0f;
        const int x0 = (int)x0f, y0 = (int)y0f;
        const int x1 = x0 + 1, y1 = y0 + 1;

        const bool vx0 = (x0 >= 0) & (x0 < WF);
        const bool vx1 = (x1 >= 0) & (x1 < WF);
        const bool vy0 = (y0 >= 0) & (y0 < HF);
        const bool vy1 = (y1 >= 0) & (y1 < HF);

        const unsigned cx0 = (unsigned)min(max(x0, 0), WF - 1);
        const unsigned cx1 = (unsigned)min(max(x1, 0), WF - 1);
        const unsigned cy0 = (unsigned)min(max(y0, 0), HF - 1);
        const unsigned cy1 = (unsigned)min(max(y1, 0), HF - 1);

        const unsigned p00 = cy0 * WF + cx0;
        const unsigned p10 = cy0 * WF + cx1;
        const unsigned p01 = cy1 * WF + cx0;
        const unsigned p11 = cy1 * WF + cx1;
        s_pixd[g][s][p][h] = make_uint2(p00 | (p10 << 16), p01 | (p11 << 16));

        const float wx0 = 1.f - lx, wy0 = 1.f - ly;
        const float w00 = (vx0 & vy0) ? wx0 * wy0 * aw : 0.f;
        const float w10 = (vx1 & vy0) ? lx  * wy0 * aw : 0.f;
        const float w01 = (vx0 & vy1) ? wx0 * ly  * aw : 0.f;
        const float w11 = (vx1 & vy1) ? lx  * ly  * aw : 0.f;
        s_wbd[g][s][p][h] = make_uint2(
            (unsigned)f2bf(w00) | ((unsigned)f2bf(w10) << 16),
            (unsigned)f2bf(w01) | ((unsigned)f2bf(w11) << 16));
    }
    __syncthreads();

    // ---- phase 2: gather — wave = 1 query, 16 lanes/head, 2 dh per lane
    {
        const char* vb = (const char*)vhw;
        const int g = t >> 6;
        const int lane = t & 63;
        const int h = lane >> 4;
        const int dhp4 = (lane & 15) * 4;   // byte offset of the dh pair
        float accx = 0.f, accy = 0.f;

        for (int s = 0; s < S_DIM; ++s) {
            if (!s_mask[g][s]) continue;
            const char* vbs = vb + (((s * H_DIM + h) * M_DIM) * (DH * 2) + dhp4);
#pragma unroll
            for (int pg = 0; pg < 4; ++pg) {   // 2 points per iter
                const uint2 pa = s_pixd[g][s][pg * 2 + 0][h];
                const uint2 pb = s_pixd[g][s][pg * 2 + 1][h];
                const unsigned u0 = *(const unsigned*)(vbs + ((pa.x <<  6) & 0x3fffc0u));
                const unsigned u1 = *(const unsigned*)(vbs + ((pa.x >> 10) & 0x3fffc0u));
                const unsigned u2 = *(const unsigned*)(vbs + ((pa.y <<  6) & 0x3fffc0u));
                const unsigned u3 = *(const unsigned*)(vbs + ((pa.y >> 10) & 0x3fffc0u));
                const unsigned u4 = *(const unsigned*)(vbs + ((pb.x <<  6) & 0x3fffc0u));
                const unsigned u5 = *(const unsigned*)(vbs + ((pb.x >> 10) & 0x3fffc0u));
                const unsigned u6 = *(const unsigned*)(vbs + ((pb.y <<  6) & 0x3fffc0u));
                const unsigned u7 = *(const unsigned*)(vbs + ((pb.y >> 10) & 0x3fffc0u));
                const uint2 wa = s_wbd[g][s][pg * 2 + 0][h];
                const uint2 wb2 = s_wbd[g][s][pg * 2 + 1][h];
                const float w00 = bfl(wa.x),  w10 = bfh(wa.x);
                const float w01 = bfl(wa.y),  w11 = bfh(wa.y);
                const float x00 = bfl(wb2.x), x10 = bfh(wb2.x);
                const float x01 = bfl(wb2.y), x11 = bfh(wb2.y);
                accx = fmaf(w00, bfl(u0), accx); accy = fmaf(w00, bfh(u0), accy);
                accx = fmaf(w10, bfl(u1), accx); accy = fmaf(w10, bfh(u1), accy);
                accx = fmaf(w01, bfl(u2), accx); accy = fmaf(w01, bfh(u2), accy);
                accx = fmaf(w11, bfl(u3), accx); accy = fmaf(w11, bfh(u3), accy);
                accx = fmaf(x00, bfl(u4), accx); accy = fmaf(x00, bfh(u4), accy);
                accx = fmaf(x10, bfl(u5), accx); accy = fmaf(x10, bfh(u5), accy);
                accx = fmaf(x01, bfl(u6), accx); accy = fmaf(x01, bfh(u6), accy);
                accx = fmaf(x11, bfl(u7), accx); accy = fmaf(x11, bfh(u7), accy);
            }
        }
        const float inv = s_inv[g];
        *(float2*)&s_slots[g][h * 32 + (lane & 15) * 2] =
            make_float2(accx * inv, accy * inv);
    }
    __syncthreads();

    // ---- phase 3: out projection + bias + residual (Wp read 2x/block)
    {
        const int c = t & 127, half = t >> 7;
        const int g0 = half * 2;
        float a0 = 0.f, a1 = 0.f;
        for (int k = 0; k < C_DIM; k += 4) {
            const float4 s0 = *(const float4*)&s_slots[g0][k];
            const float4 s1 = *(const float4*)&s_slots[g0 + 1][k];
            const float w0 = Wp[(k + 0) * C_DIM + c];
            const float w1 = Wp[(k + 1) * C_DIM + c];
            const float w2 = Wp[(k + 2) * C_DIM + c];
            const float w3 = Wp[(k + 3) * C_DIM + c];
            a0 = fmaf(s0.x, w0, a0); a1 = fmaf(s1.x, w0, a1);
            a0 = fmaf(s0.y, w1, a0); a1 = fmaf(s1.y, w1, a1);
            a0 = fmaf(s0.z, w2, a0); a1 = fmaf(s1.z, w2, a1);
            a0 = fmaf(s0.w, w3, a0); a1 = fmaf(s1.w, w3, a1);
        }
        const int na = n0 + g0;
        const float bb = bp[c];
        out[(size_t)na * C_DIM + c]       = a0 + bb + query[(size_t)na * C_DIM + c];
        out[(size_t)(na + 1) * C_DIM + c] = a1 + bb + query[(size_t)(na + 1) * C_DIM + c];
    }
}

// ---------------------------------------------------------------- launch
extern "C" void kernel_launch(void* const* d_in, const int* in_sizes, int n_in,
                              void* d_out, int out_size, void* d_ws, size_t ws_size,
                              hipStream_t stream) {
    const float* query     = (const float*)d_in[0];
    // d_in[1] = key (unused by reference)
    const float* value     = (const float*)d_in[2];
    const float* query_pos = (const float*)d_in[3];
    const float* refpts    = (const float*)d_in[4];
    const float* Wv        = (const float*)d_in[5];
    const float* bv        = (const float*)d_in[6];
    const float* Wo        = (const float*)d_in[7];
    const float* bo        = (const float*)d_in[8];
    const float* Wa        = (const float*)d_in[9];
    const float* ba        = (const float*)d_in[10];
    const float* Wp        = (const float*)d_in[11];
    const float* bp        = (const float*)d_in[12];
    const void*  sshapes   = d_in[13];
    const void*  bev_mask  = d_in[14];

    unsigned short* vhw = (unsigned short*)d_ws;
    float* outp = (float*)d_out;

    hipLaunchKernelGGL(vproj_kernel, dim3((S_DIM * M_DIM) / 32), dim3(256), 0, stream,
                       value, Wv, bv, vhw);
    hipLaunchKernelGGL(attn_kernel, dim3(N_DIM / G_Q), dim3(256), 0, stream,
                       vhw, query, query_pos, Wo, bo, Wa, ba,
                       refpts, bev_mask, sshapes, Wp, bp, outp);
}